// Round 1
// baseline (1673.431 us; speedup 1.0000x reference)
//
#include <hip/hip_runtime.h>
#include <math.h>

#define B_ 16
#define T_ 1024
#define D_ 96
#define L_ 6
#define NH_ 6
#define HS_ 16
#define FF_ 384

// ---------------- pack per-head qkv weights into [L][96][288] ----------------
__global__ __launch_bounds__(256) void pack_qkv_kernel(
    const float* __restrict__ wq, const float* __restrict__ wk,
    const float* __restrict__ wv, float* __restrict__ wpack) {
  int idx = blockIdx.x * 256 + threadIdx.x;
  const int total = L_ * 96 * 288;
  if (idx >= total) return;
  int l = idx / (96 * 288);
  int r = idx % (96 * 288);
  int d = r / 288;
  int c = r % 288;
  int which = c / 96;
  int hc = c % 96;
  int h = hc >> 4, j = hc & 15;
  const float* src = (which == 0) ? wq : (which == 1 ? wk : wv);
  wpack[idx] = src[((l * NH_ + h) * 96 + d) * 16 + j];
}

// ---------------- concat(goals, obss) -> e0 [B*T, 96] ----------------
__global__ __launch_bounds__(256) void concat_kernel(
    const float* __restrict__ goals, const float* __restrict__ obss,
    float* __restrict__ e0) {
  int idx = blockIdx.x * 256 + threadIdx.x;  // over 16384*96
  int row = idx / 96;
  int d = idx % 96;
  int b = row >> 10;
  int t = row & 1023;
  float v;
  if (d < 32) v = goals[b * 32 + d];
  else        v = obss[(size_t)(b * 1024 + t) * 64 + (d - 32)];
  e0[idx] = v;
}

// ---------------- generic fp32 GEMM: C[M,N] = A[M,K] @ W[K,N] + epilogue ----
// tile 128x32, 256 threads, 4x4 per thread. K,N multiples of 32. lda=K, ldc=N.
__global__ __launch_bounds__(256) void gemm_kernel(
    const float* __restrict__ A, int K,
    const float* __restrict__ W, int N,
    const float* __restrict__ bias,   // [N] or null
    const float* __restrict__ resid,  // [M,N] or null
    const float* __restrict__ pos,    // [T,N] or null (indexed by row&1023)
    float* __restrict__ out, int relu) {
  __shared__ float As[32][132];  // [k][m], padded
  __shared__ float Ws[32][32];
  int tid = threadIdx.x;
  int m0 = blockIdx.x * 128;
  int n0 = blockIdx.y * 32;
  int tx = tid & 7;    // 0..7  -> 4 cols
  int ty = tid >> 3;   // 0..31 -> 4 rows

  float acc[4][4];
#pragma unroll
  for (int i = 0; i < 4; ++i)
#pragma unroll
    for (int j = 0; j < 4; ++j) acc[i][j] = 0.f;

  int ra = tid >> 1;            // 0..127
  int ca = (tid & 1) * 16;      // 0 or 16
  int rw = tid >> 3;            // 0..31
  int cw = (tid & 7) * 4;       // 0..28

  for (int kk = 0; kk < K; kk += 32) {
    __syncthreads();
    // stage A tile transposed
    const float* ap = A + (size_t)(m0 + ra) * K + kk + ca;
#pragma unroll
    for (int i = 0; i < 4; ++i) {
      float4 av = *(const float4*)(ap + i * 4);
      As[ca + i * 4 + 0][ra] = av.x;
      As[ca + i * 4 + 1][ra] = av.y;
      As[ca + i * 4 + 2][ra] = av.z;
      As[ca + i * 4 + 3][ra] = av.w;
    }
    // stage W tile
    float4 wv4 = *(const float4*)(W + (size_t)(kk + rw) * N + n0 + cw);
    *(float4*)&Ws[rw][cw] = wv4;
    __syncthreads();

#pragma unroll
    for (int k = 0; k < 32; ++k) {
      float4 a = *(const float4*)&As[k][ty * 4];
      float4 w = *(const float4*)&Ws[k][tx * 4];
      acc[0][0] += a.x * w.x; acc[0][1] += a.x * w.y; acc[0][2] += a.x * w.z; acc[0][3] += a.x * w.w;
      acc[1][0] += a.y * w.x; acc[1][1] += a.y * w.y; acc[1][2] += a.y * w.z; acc[1][3] += a.y * w.w;
      acc[2][0] += a.z * w.x; acc[2][1] += a.z * w.y; acc[2][2] += a.z * w.z; acc[2][3] += a.z * w.w;
      acc[3][0] += a.w * w.x; acc[3][1] += a.w * w.y; acc[3][2] += a.w * w.z; acc[3][3] += a.w * w.w;
    }
  }

  int col0 = n0 + tx * 4;
  float bb[4] = {0.f, 0.f, 0.f, 0.f};
  if (bias) {
#pragma unroll
    for (int j = 0; j < 4; ++j) bb[j] = bias[col0 + j];
  }
#pragma unroll
  for (int i = 0; i < 4; ++i) {
    int row = m0 + ty * 4 + i;
    float4 r4;
    float v[4];
#pragma unroll
    for (int j = 0; j < 4; ++j) v[j] = acc[i][j] + bb[j];
    if (resid) {
      float4 rr = *(const float4*)(resid + (size_t)row * N + col0);
      v[0] += rr.x; v[1] += rr.y; v[2] += rr.z; v[3] += rr.w;
    }
    if (pos) {
      float4 pp = *(const float4*)(pos + (size_t)(row & 1023) * N + col0);
      v[0] += pp.x; v[1] += pp.y; v[2] += pp.z; v[3] += pp.w;
    }
    if (relu) {
#pragma unroll
      for (int j = 0; j < 4; ++j) v[j] = fmaxf(v[j], 0.f);
    }
    r4.x = v[0]; r4.y = v[1]; r4.z = v[2]; r4.w = v[3];
    *(float4*)(out + (size_t)row * N + col0) = r4;
  }
}

// ---------------- layernorm: one wave per token (96 elems) ----------------
__global__ __launch_bounds__(256) void ln_kernel(
    const float* __restrict__ x, const float* __restrict__ g,
    const float* __restrict__ b, float* __restrict__ out) {
  int wave = threadIdx.x >> 6;
  int lane = threadIdx.x & 63;
  int row = blockIdx.x * 4 + wave;
  const float* xr = x + (size_t)row * 96;
  float v0 = xr[lane];
  float v1 = (lane < 32) ? xr[64 + lane] : 0.f;
  float s = v0 + v1;
  float sq = v0 * v0 + v1 * v1;
#pragma unroll
  for (int off = 32; off > 0; off >>= 1) {
    s += __shfl_xor(s, off);
    sq += __shfl_xor(sq, off);
  }
  float mean = s * (1.f / 96.f);
  float var = sq * (1.f / 96.f) - mean * mean;
  float rs = rsqrtf(var + 1e-5f);
  float* orow = out + (size_t)row * 96;
  orow[lane] = (v0 - mean) * rs * g[lane] + b[lane];
  if (lane < 32)
    orow[64 + lane] = (v1 - mean) * rs * g[64 + lane] + b[64 + lane];
}

// ---------------- flash attention fp32: thread = one query row ----------------
// qkv: [B*T, 288] (q at +0, k at +96, v at +192, per-head 16)
// obuf: [B*T, 96]
__global__ __launch_bounds__(256) void attn_kernel(
    const float* __restrict__ qkv, float* __restrict__ obuf) {
  __shared__ float Ks[32][16];
  __shared__ float Vs[32][16];
  int bh = blockIdx.x;
  int b = bh / NH_;
  int h = bh % NH_;
  int qb = blockIdx.y;
  int tid = threadIdx.x;
  int q = qb * 256 + tid;
  int rowbase = b * 1024;

  float qr[16];
  {
    const float* qp = qkv + (size_t)(rowbase + q) * 288 + h * 16;
#pragma unroll
    for (int i = 0; i < 4; ++i) {
      float4 t4 = *(const float4*)(qp + i * 4);
      qr[i * 4 + 0] = t4.x; qr[i * 4 + 1] = t4.y;
      qr[i * 4 + 2] = t4.z; qr[i * 4 + 3] = t4.w;
    }
  }
  float m = -3e38f, l = 0.f;
  float o[16];
#pragma unroll
  for (int i = 0; i < 16; ++i) o[i] = 0.f;

  int ntiles = qb * 8 + 8;
  for (int t = 0; t < ntiles; ++t) {
    int s0 = t * 32;
    __syncthreads();
    {
      int s = (tid & 127) >> 2;
      int p = tid & 3;
      const float* src = qkv + (size_t)(rowbase + s0 + s) * 288 +
                         ((tid < 128) ? 96 : 192) + h * 16 + p * 4;
      float4 kv = *(const float4*)src;
      if (tid < 128) *(float4*)&Ks[s][p * 4] = kv;
      else           *(float4*)&Vs[s][p * 4] = kv;
    }
    __syncthreads();

    float sc[32];
#pragma unroll
    for (int s = 0; s < 32; ++s) {
      const float* kp = &Ks[s][0];
      float4 k0 = *(const float4*)(kp + 0);
      float4 k1 = *(const float4*)(kp + 4);
      float4 k2 = *(const float4*)(kp + 8);
      float4 k3 = *(const float4*)(kp + 12);
      float d = qr[0] * k0.x + qr[1] * k0.y + qr[2] * k0.z + qr[3] * k0.w +
                qr[4] * k1.x + qr[5] * k1.y + qr[6] * k1.z + qr[7] * k1.w +
                qr[8] * k2.x + qr[9] * k2.y + qr[10] * k2.z + qr[11] * k2.w +
                qr[12] * k3.x + qr[13] * k3.y + qr[14] * k3.z + qr[15] * k3.w;
      sc[s] = (s0 + s <= q) ? d * 0.25f : -3e38f;
    }
    float tm = sc[0];
#pragma unroll
    for (int s = 1; s < 32; ++s) tm = fmaxf(tm, sc[s]);
    float mn = fmaxf(m, tm);
    float corr = __expf(m - mn);
    m = mn;
    float ps = 0.f;
#pragma unroll
    for (int s = 0; s < 32; ++s) {
      sc[s] = __expf(sc[s] - mn);
      ps += sc[s];
    }
    l = l * corr + ps;
#pragma unroll
    for (int i = 0; i < 16; ++i) o[i] *= corr;
#pragma unroll
    for (int s = 0; s < 32; ++s) {
      const float* vp = &Vs[s][0];
      float4 v0 = *(const float4*)(vp + 0);
      float4 v1 = *(const float4*)(vp + 4);
      float4 v2 = *(const float4*)(vp + 8);
      float4 v3 = *(const float4*)(vp + 12);
      float p = sc[s];
      o[0] += p * v0.x;  o[1] += p * v0.y;  o[2] += p * v0.z;  o[3] += p * v0.w;
      o[4] += p * v1.x;  o[5] += p * v1.y;  o[6] += p * v1.z;  o[7] += p * v1.w;
      o[8] += p * v2.x;  o[9] += p * v2.y;  o[10] += p * v2.z; o[11] += p * v2.w;
      o[12] += p * v3.x; o[13] += p * v3.y; o[14] += p * v3.z; o[15] += p * v3.w;
    }
  }
  float inv = 1.f / l;
  float* op = obuf + (size_t)(rowbase + q) * 96 + h * 16;
#pragma unroll
  for (int i = 0; i < 4; ++i) {
    float4 w4;
    w4.x = o[i * 4 + 0] * inv; w4.y = o[i * 4 + 1] * inv;
    w4.z = o[i * 4 + 2] * inv; w4.w = o[i * 4 + 3] * inv;
    *(float4*)(op + i * 4) = w4;
  }
}

// ---------------- head: out[M,16] = xn[M,96] @ w[96,16] + b ----------------
__global__ __launch_bounds__(256) void head_kernel(
    const float* __restrict__ xn, const float* __restrict__ w,
    const float* __restrict__ bias, float* __restrict__ out) {
  __shared__ float Wsh[96 * 16];
  for (int i = threadIdx.x; i < 96 * 16; i += 256) Wsh[i] = w[i];
  __syncthreads();
  int idx = blockIdx.x * 256 + threadIdx.x;  // over 16384*16
  int row = idx >> 4;
  int c = idx & 15;
  float acc = bias[c];
  const float* xr = xn + (size_t)row * 96;
#pragma unroll
  for (int d = 0; d < 96; ++d) acc += xr[d] * Wsh[d * 16 + c];
  out[idx] = acc;
}

extern "C" void kernel_launch(void* const* d_in, const int* in_sizes, int n_in,
                              void* d_out, int out_size, void* d_ws, size_t ws_size,
                              hipStream_t stream) {
  const float* goals   = (const float*)d_in[0];
  const float* obss    = (const float*)d_in[1];
  const float* w_go    = (const float*)d_in[2];
  const float* b_go    = (const float*)d_in[3];
  const float* pos_emb = (const float*)d_in[4];
  const float* wq      = (const float*)d_in[5];
  const float* wk      = (const float*)d_in[6];
  const float* wv      = (const float*)d_in[7];
  const float* w_proj  = (const float*)d_in[8];
  const float* b_proj  = (const float*)d_in[9];
  const float* ln1_g   = (const float*)d_in[10];
  const float* ln1_b   = (const float*)d_in[11];
  const float* ln2_g   = (const float*)d_in[12];
  const float* ln2_b   = (const float*)d_in[13];
  const float* w_ff1   = (const float*)d_in[14];
  const float* b_ff1   = (const float*)d_in[15];
  const float* w_ff2   = (const float*)d_in[16];
  const float* b_ff2   = (const float*)d_in[17];
  const float* lnf_g   = (const float*)d_in[18];
  const float* lnf_b   = (const float*)d_in[19];
  const float* w_act   = (const float*)d_in[20];
  const float* b_act   = (const float*)d_in[21];
  float* out = (float*)d_out;

  const int M = B_ * T_;  // 16384
  float* ws = (float*)d_ws;
  size_t off = 0;
  float* wpack = ws + off; off += (size_t)L_ * 96 * 288;
  float* e0    = ws + off; off += (size_t)M * 96;
  float* x     = ws + off; off += (size_t)M * 96;
  float* xn    = ws + off; off += (size_t)M * 96;
  float* qkvb  = ws + off; off += (size_t)M * 288;
  float* ob    = ws + off; off += (size_t)M * 96;
  float* f1    = ws + off; off += (size_t)M * 384;

  pack_qkv_kernel<<<(L_ * 96 * 288) / 256, 256, 0, stream>>>(wq, wk, wv, wpack);
  concat_kernel<<<(M * 96) / 256, 256, 0, stream>>>(goals, obss, e0);
  // x = e0 @ w_go + b_go + pos
  gemm_kernel<<<dim3(M / 128, 3), 256, 0, stream>>>(e0, 96, w_go, 96, b_go,
                                                    nullptr, pos_emb, x, 0);
  for (int l = 0; l < L_; ++l) {
    ln_kernel<<<M / 4, 256, 0, stream>>>(x, ln1_g + l * 96, ln1_b + l * 96, xn);
    gemm_kernel<<<dim3(M / 128, 9), 256, 0, stream>>>(
        xn, 96, wpack + (size_t)l * 96 * 288, 288, nullptr, nullptr, nullptr,
        qkvb, 0);
    attn_kernel<<<dim3(B_ * NH_, T_ / 256), 256, 0, stream>>>(qkvb, ob);
    gemm_kernel<<<dim3(M / 128, 3), 256, 0, stream>>>(
        ob, 96, w_proj + (size_t)l * 96 * 96, 96, b_proj + l * 96, x, nullptr,
        x, 0);
    ln_kernel<<<M / 4, 256, 0, stream>>>(x, ln2_g + l * 96, ln2_b + l * 96, xn);
    gemm_kernel<<<dim3(M / 128, 12), 256, 0, stream>>>(
        xn, 96, w_ff1 + (size_t)l * 96 * 384, 384, b_ff1 + l * 384, nullptr,
        nullptr, f1, 1);
    gemm_kernel<<<dim3(M / 128, 3), 256, 0, stream>>>(
        f1, 384, w_ff2 + (size_t)l * 384 * 96, 96, b_ff2 + l * 96, x, nullptr,
        x, 0);
  }
  ln_kernel<<<M / 4, 256, 0, stream>>>(x, lnf_g, lnf_b, xn);
  head_kernel<<<(M * 16) / 256, 256, 0, stream>>>(xn, w_act, b_act, out);
}

// Round 2
// 771.167 us; speedup vs baseline: 2.1700x; 2.1700x over previous
//
#include <hip/hip_runtime.h>
#include <math.h>

#define B_ 16
#define T_ 1024
#define D_ 96
#define L_ 6
#define NH_ 6
#define HS_ 16
#define FF_ 384

typedef _Float16 half4 __attribute__((ext_vector_type(4)));
typedef float floatx4 __attribute__((ext_vector_type(4)));

// ---------------- pack per-head qkv weights into [L][96][288] ----------------
__global__ __launch_bounds__(256) void pack_qkv_kernel(
    const float* __restrict__ wq, const float* __restrict__ wk,
    const float* __restrict__ wv, float* __restrict__ wpack) {
  int idx = blockIdx.x * 256 + threadIdx.x;
  const int total = L_ * 96 * 288;
  if (idx >= total) return;
  int l = idx / (96 * 288);
  int r = idx % (96 * 288);
  int d = r / 288;
  int c = r % 288;
  int which = c / 96;
  int hc = c % 96;
  int h = hc >> 4, j = hc & 15;
  const float* src = (which == 0) ? wq : (which == 1 ? wk : wv);
  wpack[idx] = src[((l * NH_ + h) * 96 + d) * 16 + j];
}

// ---------------- concat(goals, obss) -> e0 [B*T, 96] ----------------
__global__ __launch_bounds__(256) void concat_kernel(
    const float* __restrict__ goals, const float* __restrict__ obss,
    float* __restrict__ e0) {
  int idx = blockIdx.x * 256 + threadIdx.x;  // over 16384*96
  int row = idx / 96;
  int d = idx % 96;
  int b = row >> 10;
  int t = row & 1023;
  float v;
  if (d < 32) v = goals[b * 32 + d];
  else        v = obss[(size_t)(b * 1024 + t) * 64 + (d - 32)];
  e0[idx] = v;
}

// ---------------- generic fp32 GEMM: C[M,N] = A[M,K] @ W[K,N] + epilogue ----
// tile 128x32, 256 threads, 4x4 per thread. K,N multiples of 32. lda=K, ldc=N.
// mode 0: fp32 out with bias/resid/pos/relu.
// mode 1: qkv pack: cols [0,96)->Qh f16 [bh][t][16], [96,192)->Kh, [192,288)->Vt f16 [bh][d][1024]
__global__ __launch_bounds__(256) void gemm_kernel(
    const float* __restrict__ A, int K,
    const float* __restrict__ W, int N,
    const float* __restrict__ bias,   // [N] or null
    const float* __restrict__ resid,  // [M,N] or null
    const float* __restrict__ pos,    // [T,N] or null (indexed by row&1023)
    float* __restrict__ out, int relu, int mode,
    _Float16* __restrict__ qh, _Float16* __restrict__ kh,
    _Float16* __restrict__ vt) {
  __shared__ float As[32][132];  // [k][m], padded
  __shared__ float Ws[32][32];
  int tid = threadIdx.x;
  int m0 = blockIdx.x * 128;
  int n0 = blockIdx.y * 32;
  int tx = tid & 7;    // 0..7  -> 4 cols
  int ty = tid >> 3;   // 0..31 -> 4 rows

  float acc[4][4];
#pragma unroll
  for (int i = 0; i < 4; ++i)
#pragma unroll
    for (int j = 0; j < 4; ++j) acc[i][j] = 0.f;

  int ra = tid >> 1;            // 0..127
  int ca = (tid & 1) * 16;      // 0 or 16
  int rw = tid >> 3;            // 0..31
  int cw = (tid & 7) * 4;       // 0..28

  for (int kk = 0; kk < K; kk += 32) {
    __syncthreads();
    const float* ap = A + (size_t)(m0 + ra) * K + kk + ca;
#pragma unroll
    for (int i = 0; i < 4; ++i) {
      float4 av = *(const float4*)(ap + i * 4);
      As[ca + i * 4 + 0][ra] = av.x;
      As[ca + i * 4 + 1][ra] = av.y;
      As[ca + i * 4 + 2][ra] = av.z;
      As[ca + i * 4 + 3][ra] = av.w;
    }
    float4 wv4 = *(const float4*)(W + (size_t)(kk + rw) * N + n0 + cw);
    *(float4*)&Ws[rw][cw] = wv4;
    __syncthreads();

#pragma unroll
    for (int k = 0; k < 32; ++k) {
      float4 a = *(const float4*)&As[k][ty * 4];
      float4 w = *(const float4*)&Ws[k][tx * 4];
      acc[0][0] += a.x * w.x; acc[0][1] += a.x * w.y; acc[0][2] += a.x * w.z; acc[0][3] += a.x * w.w;
      acc[1][0] += a.y * w.x; acc[1][1] += a.y * w.y; acc[1][2] += a.y * w.z; acc[1][3] += a.y * w.w;
      acc[2][0] += a.z * w.x; acc[2][1] += a.z * w.y; acc[2][2] += a.z * w.z; acc[2][3] += a.z * w.w;
      acc[3][0] += a.w * w.x; acc[3][1] += a.w * w.y; acc[3][2] += a.w * w.z; acc[3][3] += a.w * w.w;
    }
  }

  if (mode == 1) {
    int row0 = m0 + ty * 4;
    int b = row0 >> 10;
    int t0 = row0 & 1023;
    int c0 = n0 + tx * 4;
    int which = c0 / 96;
    int hd = c0 % 96;
    int h = hd >> 4, d0 = hd & 15;
    int bh = b * NH_ + h;
    if (which < 2) {
      _Float16* dst = (which == 0 ? qh : kh) + (size_t)bh * 1024 * 16;
#pragma unroll
      for (int i = 0; i < 4; ++i) {
        half4 hv = {(_Float16)acc[i][0], (_Float16)acc[i][1],
                    (_Float16)acc[i][2], (_Float16)acc[i][3]};
        *(half4*)(dst + (size_t)(t0 + i) * 16 + d0) = hv;
      }
    } else {
      _Float16* dst = vt + (size_t)bh * 16 * 1024;
#pragma unroll
      for (int j = 0; j < 4; ++j) {
        half4 hv = {(_Float16)acc[0][j], (_Float16)acc[1][j],
                    (_Float16)acc[2][j], (_Float16)acc[3][j]};
        *(half4*)(dst + (size_t)(d0 + j) * 1024 + t0) = hv;
      }
    }
    return;
  }

  int col0 = n0 + tx * 4;
  float bb[4] = {0.f, 0.f, 0.f, 0.f};
  if (bias) {
#pragma unroll
    for (int j = 0; j < 4; ++j) bb[j] = bias[col0 + j];
  }
#pragma unroll
  for (int i = 0; i < 4; ++i) {
    int row = m0 + ty * 4 + i;
    float4 r4;
    float v[4];
#pragma unroll
    for (int j = 0; j < 4; ++j) v[j] = acc[i][j] + bb[j];
    if (resid) {
      float4 rr = *(const float4*)(resid + (size_t)row * N + col0);
      v[0] += rr.x; v[1] += rr.y; v[2] += rr.z; v[3] += rr.w;
    }
    if (pos) {
      float4 pp = *(const float4*)(pos + (size_t)(row & 1023) * N + col0);
      v[0] += pp.x; v[1] += pp.y; v[2] += pp.z; v[3] += pp.w;
    }
    if (relu) {
#pragma unroll
      for (int j = 0; j < 4; ++j) v[j] = fmaxf(v[j], 0.f);
    }
    r4.x = v[0]; r4.y = v[1]; r4.z = v[2]; r4.w = v[3];
    *(float4*)(out + (size_t)row * N + col0) = r4;
  }
}

// ---------------- layernorm: one wave per token (96 elems) ----------------
__global__ __launch_bounds__(256) void ln_kernel(
    const float* __restrict__ x, const float* __restrict__ g,
    const float* __restrict__ b, float* __restrict__ out) {
  int wave = threadIdx.x >> 6;
  int lane = threadIdx.x & 63;
  int row = blockIdx.x * 4 + wave;
  const float* xr = x + (size_t)row * 96;
  float v0 = xr[lane];
  float v1 = (lane < 32) ? xr[64 + lane] : 0.f;
  float s = v0 + v1;
  float sq = v0 * v0 + v1 * v1;
#pragma unroll
  for (int off = 32; off > 0; off >>= 1) {
    s += __shfl_xor(s, off);
    sq += __shfl_xor(sq, off);
  }
  float mean = s * (1.f / 96.f);
  float var = sq * (1.f / 96.f) - mean * mean;
  float rs = rsqrtf(var + 1e-5f);
  float* orow = out + (size_t)row * 96;
  orow[lane] = (v0 - mean) * rs * g[lane] + b[lane];
  if (lane < 32)
    orow[64 + lane] = (v1 - mean) * rs * g[64 + lane] + b[64 + lane];
}

// ---------------- MFMA f16 flash attention ----------------
// Qh,Kh: [bh][t][16] f16; Vt: [bh][d][1024] f16; ob: [B*T,96] f32
// One wave = 32 query rows (two 16-row subtiles), kv tiles of 32.
// Uses v_mfma_f32_16x16x16_f16. Chained layout: D of S^T=mfma(K,Q) is the
// A-operand layout of P for O+=mfma(P,V).
__global__ __launch_bounds__(256) void attn_mfma_kernel(
    const _Float16* __restrict__ Qh, const _Float16* __restrict__ Kh,
    const _Float16* __restrict__ Vt, float* __restrict__ ob) {
  int bh = blockIdx.x;                 // 0..95
  int wave = threadIdx.x >> 6;
  int lane = threadIdx.x & 63;
  int qt = wave * 8 + blockIdx.y;      // 0..31 (interleaved for balance)
  int q0 = qt * 32;
  int lr = lane & 15;
  int lg = lane >> 4;

  const _Float16* qb = Qh + (size_t)bh * 1024 * 16;
  const _Float16* kb = Kh + (size_t)bh * 1024 * 16;
  const _Float16* vb = Vt + (size_t)bh * 16 * 1024;

  // Q fragments (B-operand layout), pre-scaled by 1/sqrt(16)=0.25
  half4 qf[2];
#pragma unroll
  for (int u = 0; u < 2; ++u) {
    half4 qv = *(const half4*)(qb + (size_t)(q0 + u * 16 + lr) * 16 + lg * 4);
#pragma unroll
    for (int j = 0; j < 4; ++j) qv[j] = qv[j] * (_Float16)0.25f;
    qf[u] = qv;
  }

  floatx4 O[2] = {{0.f, 0.f, 0.f, 0.f}, {0.f, 0.f, 0.f, 0.f}};
  float m_[2] = {-1e30f, -1e30f};
  float l_[2] = {0.f, 0.f};
  const floatx4 zero4 = {0.f, 0.f, 0.f, 0.f};

  int ntiles = qt + 1;
  for (int tt = 0; tt < ntiles; ++tt) {
    int s0 = tt * 32;
    bool last = (tt == ntiles - 1);
    half4 kf0 = *(const half4*)(kb + (size_t)(s0 + lr) * 16 + lg * 4);
    half4 kf1 = *(const half4*)(kb + (size_t)(s0 + 16 + lr) * 16 + lg * 4);
    half4 vf0 = *(const half4*)(vb + (size_t)lr * 1024 + s0 + lg * 4);
    half4 vf1 = *(const half4*)(vb + (size_t)lr * 1024 + s0 + 16 + lg * 4);
#pragma unroll
    for (int u = 0; u < 2; ++u) {
      int qu = q0 + u * 16;
      bool act1 = (s0 + 16 <= qu + 15);
      // lane holds S[q=qu+lr][s=s0(+16)+lg*4+r]
      floatx4 st0 = __builtin_amdgcn_mfma_f32_16x16x16f16(kf0, qf[u], zero4, 0, 0, 0);
      floatx4 st1;
      if (act1)
        st1 = __builtin_amdgcn_mfma_f32_16x16x16f16(kf1, qf[u], zero4, 0, 0, 0);
      else
        st1 = (floatx4){-1e30f, -1e30f, -1e30f, -1e30f};
      if (last) {
        int qidx = qu + lr;
#pragma unroll
        for (int r = 0; r < 4; ++r) {
          if (s0 + lg * 4 + r > qidx) st0[r] = -1e30f;
          if (s0 + 16 + lg * 4 + r > qidx) st1[r] = -1e30f;
        }
      }
      float mx = fmaxf(fmaxf(fmaxf(st0[0], st0[1]), fmaxf(st0[2], st0[3])),
                       fmaxf(fmaxf(st1[0], st1[1]), fmaxf(st1[2], st1[3])));
      mx = fmaxf(mx, __shfl_xor(mx, 16));
      mx = fmaxf(mx, __shfl_xor(mx, 32));
      float mn = fmaxf(m_[u], mx);
      float corr = __expf(m_[u] - mn);
      m_[u] = mn;
      float p0[4], p1[4];
      float ps = 0.f;
#pragma unroll
      for (int r = 0; r < 4; ++r) { p0[r] = __expf(st0[r] - mn); ps += p0[r]; }
      if (act1) {
#pragma unroll
        for (int r = 0; r < 4; ++r) { p1[r] = __expf(st1[r] - mn); ps += p1[r]; }
      }
      ps += __shfl_xor(ps, 16);
      ps += __shfl_xor(ps, 32);
      l_[u] = l_[u] * corr + ps;
      // rescale O: reg r holds q_local = lg*4+r -> corr from lane lg*4+r
#pragma unroll
      for (int r = 0; r < 4; ++r) {
        float c = __shfl(corr, lg * 4 + r);
        O[u][r] *= c;
      }
      half4 pf0 = {(_Float16)p0[0], (_Float16)p0[1], (_Float16)p0[2], (_Float16)p0[3]};
      O[u] = __builtin_amdgcn_mfma_f32_16x16x16f16(pf0, vf0, O[u], 0, 0, 0);
      if (act1) {
        half4 pf1 = {(_Float16)p1[0], (_Float16)p1[1], (_Float16)p1[2], (_Float16)p1[3]};
        O[u] = __builtin_amdgcn_mfma_f32_16x16x16f16(pf1, vf1, O[u], 0, 0, 0);
      }
    }
  }
  int b = bh / NH_, h = bh % NH_;
#pragma unroll
  for (int u = 0; u < 2; ++u) {
    float linv = 1.f / l_[u];
#pragma unroll
    for (int r = 0; r < 4; ++r) {
      float li = __shfl(linv, lg * 4 + r);
      int q = q0 + u * 16 + lg * 4 + r;
      ob[(size_t)(b * 1024 + q) * 96 + h * 16 + lr] = O[u][r] * li;
    }
  }
}

// ---------------- head: out[M,16] = xn[M,96] @ w[96,16] + b ----------------
__global__ __launch_bounds__(256) void head_kernel(
    const float* __restrict__ xn, const float* __restrict__ w,
    const float* __restrict__ bias, float* __restrict__ out) {
  __shared__ float Wsh[96 * 16];
  for (int i = threadIdx.x; i < 96 * 16; i += 256) Wsh[i] = w[i];
  __syncthreads();
  int idx = blockIdx.x * 256 + threadIdx.x;  // over 16384*16
  int row = idx >> 4;
  int c = idx & 15;
  float acc = bias[c];
  const float* xr = xn + (size_t)row * 96;
#pragma unroll
  for (int d = 0; d < 96; ++d) acc += xr[d] * Wsh[d * 16 + c];
  out[idx] = acc;
}

extern "C" void kernel_launch(void* const* d_in, const int* in_sizes, int n_in,
                              void* d_out, int out_size, void* d_ws, size_t ws_size,
                              hipStream_t stream) {
  const float* goals   = (const float*)d_in[0];
  const float* obss    = (const float*)d_in[1];
  const float* w_go    = (const float*)d_in[2];
  const float* b_go    = (const float*)d_in[3];
  const float* pos_emb = (const float*)d_in[4];
  const float* wq      = (const float*)d_in[5];
  const float* wk      = (const float*)d_in[6];
  const float* wv      = (const float*)d_in[7];
  const float* w_proj  = (const float*)d_in[8];
  const float* b_proj  = (const float*)d_in[9];
  const float* ln1_g   = (const float*)d_in[10];
  const float* ln1_b   = (const float*)d_in[11];
  const float* ln2_g   = (const float*)d_in[12];
  const float* ln2_b   = (const float*)d_in[13];
  const float* w_ff1   = (const float*)d_in[14];
  const float* b_ff1   = (const float*)d_in[15];
  const float* w_ff2   = (const float*)d_in[16];
  const float* b_ff2   = (const float*)d_in[17];
  const float* lnf_g   = (const float*)d_in[18];
  const float* lnf_b   = (const float*)d_in[19];
  const float* w_act   = (const float*)d_in[20];
  const float* b_act   = (const float*)d_in[21];
  float* out = (float*)d_out;

  const int M = B_ * T_;  // 16384
  float* ws = (float*)d_ws;
  size_t off = 0;
  float* wpack = ws + off; off += (size_t)L_ * 96 * 288;
  float* e0    = ws + off; off += (size_t)M * 96;
  float* x     = ws + off; off += (size_t)M * 96;
  float* xn    = ws + off; off += (size_t)M * 96;
  float* ob    = ws + off; off += (size_t)M * 96;
  float* f1    = ws + off; off += (size_t)M * 384;
  _Float16* Qh = (_Float16*)(ws + off); off += (size_t)M * 48;  // 96*1024*16 halves
  _Float16* Kh = (_Float16*)(ws + off); off += (size_t)M * 48;
  _Float16* Vt = (_Float16*)(ws + off); off += (size_t)M * 48;

  pack_qkv_kernel<<<(L_ * 96 * 288) / 256, 256, 0, stream>>>(wq, wk, wv, wpack);
  concat_kernel<<<(M * 96) / 256, 256, 0, stream>>>(goals, obss, e0);
  // x = e0 @ w_go + b_go + pos
  gemm_kernel<<<dim3(M / 128, 3), 256, 0, stream>>>(
      e0, 96, w_go, 96, b_go, nullptr, pos_emb, x, 0, 0, nullptr, nullptr, nullptr);
  for (int l = 0; l < L_; ++l) {
    ln_kernel<<<M / 4, 256, 0, stream>>>(x, ln1_g + l * 96, ln1_b + l * 96, xn);
    gemm_kernel<<<dim3(M / 128, 9), 256, 0, stream>>>(
        xn, 96, wpack + (size_t)l * 96 * 288, 288, nullptr, nullptr, nullptr,
        nullptr, 0, 1, Qh, Kh, Vt);
    attn_mfma_kernel<<<dim3(B_ * NH_, 8), 256, 0, stream>>>(Qh, Kh, Vt, ob);
    gemm_kernel<<<dim3(M / 128, 3), 256, 0, stream>>>(
        ob, 96, w_proj + (size_t)l * 96 * 96, 96, b_proj + l * 96, x, nullptr,
        x, 0, 0, nullptr, nullptr, nullptr);
    ln_kernel<<<M / 4, 256, 0, stream>>>(x, ln2_g + l * 96, ln2_b + l * 96, xn);
    gemm_kernel<<<dim3(M / 128, 12), 256, 0, stream>>>(
        xn, 96, w_ff1 + (size_t)l * 96 * 384, 384, b_ff1 + l * 384, nullptr,
        nullptr, f1, 1, 0, nullptr, nullptr, nullptr);
    gemm_kernel<<<dim3(M / 128, 3), 256, 0, stream>>>(
        f1, 384, w_ff2 + (size_t)l * 384 * 96, 96, b_ff2 + l * 96, x, nullptr,
        x, 0, 0, nullptr, nullptr, nullptr);
  }
  ln_kernel<<<M / 4, 256, 0, stream>>>(x, lnf_g, lnf_b, xn);
  head_kernel<<<(M * 16) / 256, 256, 0, stream>>>(xn, w_act, b_act, out);
}

// Round 3
// 568.935 us; speedup vs baseline: 2.9413x; 1.3555x over previous
//
#include <hip/hip_runtime.h>
#include <math.h>

#define B_ 16
#define T_ 1024
#define D_ 96
#define L_ 6
#define NH_ 6
#define HS_ 16
#define FF_ 384

typedef _Float16 h4 __attribute__((ext_vector_type(4)));
typedef float f4 __attribute__((ext_vector_type(4)));

// packed f16 W^T buffer segment offsets (in halves)
#define OFF_GO   0
#define OFF_QKV  9216
#define OFF_PROJ 175104
#define OFF_FF1  230400
#define OFF_FF2  451584
#define OFF_ACT  672768
#define PACK_TOTAL 674304  // = 2634 * 256

enum { EPI_POS = 0, EPI_QKV = 1, EPI_RESID = 2, EPI_RELUH = 3, EPI_OUT = 4 };

// ---------- pack all weights -> f16 W^T [N][K] ----------
__global__ __launch_bounds__(256) void pack_all_kernel(
    const float* __restrict__ w_go, const float* __restrict__ wq,
    const float* __restrict__ wk, const float* __restrict__ wv,
    const float* __restrict__ w_proj, const float* __restrict__ w_ff1,
    const float* __restrict__ w_ff2, const float* __restrict__ w_act,
    _Float16* __restrict__ P) {
  int i = blockIdx.x * 256 + threadIdx.x;
  if (i >= PACK_TOTAL) return;
  float v;
  if (i < OFF_QKV) {                       // w_go [96k][96n] -> [n][k]
    int o = i, n = o / 96, k = o % 96;
    v = w_go[k * 96 + n];
  } else if (i < OFF_PROJ) {               // wq/wk/wv [l][h][d][j] -> [l][c][d]
    int o = i - OFF_QKV;
    int l = o / 27648, r = o % 27648, c = r / 96, d = r % 96;
    int which = c / 96 * 0 + c / 96;       // c in [0,288)
    which = c / 96;
    int hc = c % 96, h = hc >> 4, j = hc & 15;
    const float* s = (which == 0) ? wq : (which == 1 ? wk : wv);
    v = s[((l * NH_ + h) * 96 + d) * 16 + j];
  } else if (i < OFF_FF1) {                // w_proj [l][96k][96n]
    int o = i - OFF_PROJ;
    int l = o / 9216, r = o % 9216, n = r / 96, k = r % 96;
    v = w_proj[l * 9216 + k * 96 + n];
  } else if (i < OFF_FF2) {                // w_ff1 [l][96k][384n]
    int o = i - OFF_FF1;
    int l = o / 36864, r = o % 36864, n = r / 96, k = r % 96;
    v = w_ff1[l * 36864 + k * 384 + n];
  } else if (i < OFF_ACT) {                // w_ff2 [l][384k][96n]
    int o = i - OFF_FF2;
    int l = o / 36864, r = o % 36864, n = r / 384, k = r % 384;
    v = w_ff2[l * 36864 + k * 96 + n];
  } else {                                 // w_act [96k][16n]
    int o = i - OFF_ACT;
    int n = o / 96, k = o % 96;
    v = w_act[k * 16 + n];
  }
  P[i] = (_Float16)v;
}

// ---------- concat(goals, obss) -> e0h [B*T, 96] f16 ----------
__global__ __launch_bounds__(256) void concat_kernel(
    const float* __restrict__ goals, const float* __restrict__ obss,
    _Float16* __restrict__ e0h) {
  int idx = blockIdx.x * 256 + threadIdx.x;  // over 16384*96
  int row = idx / 96;
  int d = idx % 96;
  int b = row >> 10;
  int t = row & 1023;
  float v;
  if (d < 32) v = goals[b * 32 + d];
  else        v = obss[(size_t)(b * 1024 + t) * 64 + (d - 32)];
  e0h[idx] = (_Float16)v;
}

// ---------- f16 MFMA GEMM, block=256 (4 waves), wave = 16 rows x NFRAGS*16 cols
// A: f16 [M][K] (or fp32 x with fused LN when LNF). Wt: f16 [N][K] packed.
// grid.x = M/64, grid.y = N/(NFRAGS*16).
template <int KSTEPS, int NFRAGS, bool LNF, int EPI>
__global__ __launch_bounds__(256) void gemm16(
    const void* __restrict__ Ain, const _Float16* __restrict__ Wt,
    const float* __restrict__ bias, const float* resid,
    const float* __restrict__ pos, const float* __restrict__ lng,
    const float* __restrict__ lnb, float* outf, _Float16* __restrict__ outh,
    _Float16* __restrict__ qh, _Float16* __restrict__ kh,
    _Float16* __restrict__ vt, int ldo) {
  constexpr int K = KSTEPS * 16;
  int tid = threadIdx.x;
  int wave = tid >> 6, lane = tid & 63;
  int lr = lane & 15, lg = lane >> 4;
  int row0 = blockIdx.x * 64 + wave * 16;
  int n0 = blockIdx.y * (NFRAGS * 16);
  int arow = row0 + lr;

  h4 af[KSTEPS];
  if constexpr (LNF) {
    static_assert(KSTEPS == 6, "LN fuse requires K=96");
    const float* xr = (const float*)Ain + (size_t)arow * 96 + lg * 4;
    float v[6][4];
    float s = 0.f, sq = 0.f;
#pragma unroll
    for (int st = 0; st < 6; ++st) {
      f4 t4 = *(const f4*)(xr + st * 16);
#pragma unroll
      for (int j = 0; j < 4; ++j) {
        v[st][j] = t4[j];
        s += t4[j];
        sq += t4[j] * t4[j];
      }
    }
    s += __shfl_xor(s, 16); sq += __shfl_xor(sq, 16);
    s += __shfl_xor(s, 32); sq += __shfl_xor(sq, 32);
    float mean = s * (1.f / 96.f);
    float rs = rsqrtf(sq * (1.f / 96.f) - mean * mean + 1e-5f);
#pragma unroll
    for (int st = 0; st < 6; ++st) {
      f4 g4 = *(const f4*)(lng + st * 16 + lg * 4);
      f4 b4 = *(const f4*)(lnb + st * 16 + lg * 4);
#pragma unroll
      for (int j = 0; j < 4; ++j)
        af[st][j] = (_Float16)((v[st][j] - mean) * rs * g4[j] + b4[j]);
    }
  } else {
    const _Float16* ar = (const _Float16*)Ain + (size_t)arow * K + lg * 4;
#pragma unroll
    for (int st = 0; st < KSTEPS; ++st)
      af[st] = *(const h4*)(ar + st * 16);
  }

  f4 acc[NFRAGS];
#pragma unroll
  for (int nf = 0; nf < NFRAGS; ++nf) acc[nf] = (f4){0.f, 0.f, 0.f, 0.f};

  const _Float16* wb = Wt + (size_t)(n0 + lr) * K + lg * 4;
#pragma unroll
  for (int st = 0; st < KSTEPS; ++st) {
#pragma unroll
    for (int nf = 0; nf < NFRAGS; ++nf) {
      h4 wf = *(const h4*)(wb + (size_t)nf * 16 * K + st * 16);
      acc[nf] = __builtin_amdgcn_mfma_f32_16x16x16f16(af[st], wf, acc[nf], 0, 0, 0);
    }
  }

  // D layout: col = n0 + nf*16 + (lane&15); row = row0 + (lane>>4)*4 + r
  if constexpr (EPI == EPI_QKV) {
    int b = row0 >> 10;
    int t0 = row0 & 1023;
    int which = blockIdx.y;  // 0=Q, 1=K, 2=V (N blocked by 96)
#pragma unroll
    for (int nf = 0; nf < NFRAGS; ++nf) {
      int bh = b * NH_ + nf;
      if (which < 2) {
        _Float16* dst = (which == 0 ? qh : kh) + (size_t)bh * 1024 * 16 + lr;
#pragma unroll
        for (int r = 0; r < 4; ++r)
          dst[(size_t)(t0 + lg * 4 + r) * 16] = (_Float16)acc[nf][r];
      } else {
        _Float16* dst = vt + (size_t)bh * 16 * 1024 + (size_t)lr * 1024 + t0 + lg * 4;
#pragma unroll
        for (int r = 0; r < 4; ++r) dst[r] = (_Float16)acc[nf][r];
      }
    }
  } else {
#pragma unroll
    for (int nf = 0; nf < NFRAGS; ++nf) {
      int col = n0 + nf * 16 + lr;
      float bb = bias[col];
#pragma unroll
      for (int r = 0; r < 4; ++r) {
        int row = row0 + lg * 4 + r;
        float vv = acc[nf][r] + bb;
        if constexpr (EPI == EPI_RELUH) {
          outh[(size_t)row * ldo + col] = (_Float16)fmaxf(vv, 0.f);
        } else {
          if constexpr (EPI == EPI_POS)
            vv += pos[(size_t)(row & 1023) * 96 + col];
          if constexpr (EPI == EPI_RESID)
            vv += resid[(size_t)row * 96 + col];
          outf[(size_t)row * ldo + col] = vv;
        }
      }
    }
  }
}

// ---------- MFMA f16 flash attention (reg double-buffered K/V prefetch) ------
__global__ __launch_bounds__(256) void attn_mfma_kernel(
    const _Float16* __restrict__ Qh, const _Float16* __restrict__ Kh,
    const _Float16* __restrict__ Vt, _Float16* __restrict__ obh) {
  int bh = blockIdx.x;                 // 0..95
  int wave = threadIdx.x >> 6;
  int lane = threadIdx.x & 63;
  int qt = wave * 8 + blockIdx.y;      // 0..31
  int q0 = qt * 32;
  int lr = lane & 15;
  int lg = lane >> 4;

  const _Float16* qb = Qh + (size_t)bh * 1024 * 16;
  const _Float16* kb = Kh + (size_t)bh * 1024 * 16;
  const _Float16* vb = Vt + (size_t)bh * 16 * 1024;

  h4 qf[2];
#pragma unroll
  for (int u = 0; u < 2; ++u) {
    h4 qv = *(const h4*)(qb + (size_t)(q0 + u * 16 + lr) * 16 + lg * 4);
#pragma unroll
    for (int j = 0; j < 4; ++j) qv[j] = qv[j] * (_Float16)0.25f;
    qf[u] = qv;
  }

  f4 O[2] = {{0.f, 0.f, 0.f, 0.f}, {0.f, 0.f, 0.f, 0.f}};
  float m_[2] = {-1e30f, -1e30f};
  float l_[2] = {0.f, 0.f};
  const f4 zero4 = {0.f, 0.f, 0.f, 0.f};

  int ntiles = qt + 1;
  h4 kc0, kc1, vc0, vc1, kn0, kn1, vn0, vn1;
  kc0 = *(const h4*)(kb + (size_t)lr * 16 + lg * 4);
  kc1 = *(const h4*)(kb + (size_t)(16 + lr) * 16 + lg * 4);
  vc0 = *(const h4*)(vb + (size_t)lr * 1024 + lg * 4);
  vc1 = *(const h4*)(vb + (size_t)lr * 1024 + 16 + lg * 4);

  for (int tt = 0; tt < ntiles; ++tt) {
    int s0 = tt * 32;
    bool last = (tt == ntiles - 1);
    if (!last) {
      int s1 = s0 + 32;
      kn0 = *(const h4*)(kb + (size_t)(s1 + lr) * 16 + lg * 4);
      kn1 = *(const h4*)(kb + (size_t)(s1 + 16 + lr) * 16 + lg * 4);
      vn0 = *(const h4*)(vb + (size_t)lr * 1024 + s1 + lg * 4);
      vn1 = *(const h4*)(vb + (size_t)lr * 1024 + s1 + 16 + lg * 4);
    }
#pragma unroll
    for (int u = 0; u < 2; ++u) {
      int qu = q0 + u * 16;
      bool act1 = (s0 + 16 <= qu + 15);
      f4 st0 = __builtin_amdgcn_mfma_f32_16x16x16f16(kc0, qf[u], zero4, 0, 0, 0);
      f4 st1;
      if (act1)
        st1 = __builtin_amdgcn_mfma_f32_16x16x16f16(kc1, qf[u], zero4, 0, 0, 0);
      else
        st1 = (f4){-1e30f, -1e30f, -1e30f, -1e30f};
      if (last) {
        int qidx = qu + lr;
#pragma unroll
        for (int r = 0; r < 4; ++r) {
          if (s0 + lg * 4 + r > qidx) st0[r] = -1e30f;
          if (s0 + 16 + lg * 4 + r > qidx) st1[r] = -1e30f;
        }
      }
      float mx = fmaxf(fmaxf(fmaxf(st0[0], st0[1]), fmaxf(st0[2], st0[3])),
                       fmaxf(fmaxf(st1[0], st1[1]), fmaxf(st1[2], st1[3])));
      mx = fmaxf(mx, __shfl_xor(mx, 16));
      mx = fmaxf(mx, __shfl_xor(mx, 32));
      float mn = fmaxf(m_[u], mx);
      float corr = __expf(m_[u] - mn);
      m_[u] = mn;
      float p0[4], p1[4];
      float ps = 0.f;
#pragma unroll
      for (int r = 0; r < 4; ++r) { p0[r] = __expf(st0[r] - mn); ps += p0[r]; }
      if (act1) {
#pragma unroll
        for (int r = 0; r < 4; ++r) { p1[r] = __expf(st1[r] - mn); ps += p1[r]; }
      }
      ps += __shfl_xor(ps, 16);
      ps += __shfl_xor(ps, 32);
      l_[u] = l_[u] * corr + ps;
#pragma unroll
      for (int r = 0; r < 4; ++r) {
        float c = __shfl(corr, lg * 4 + r);
        O[u][r] *= c;
      }
      h4 pf0 = {(_Float16)p0[0], (_Float16)p0[1], (_Float16)p0[2], (_Float16)p0[3]};
      O[u] = __builtin_amdgcn_mfma_f32_16x16x16f16(pf0, vc0, O[u], 0, 0, 0);
      if (act1) {
        h4 pf1 = {(_Float16)p1[0], (_Float16)p1[1], (_Float16)p1[2], (_Float16)p1[3]};
        O[u] = __builtin_amdgcn_mfma_f32_16x16x16f16(pf1, vc1, O[u], 0, 0, 0);
      }
    }
    if (!last) { kc0 = kn0; kc1 = kn1; vc0 = vn0; vc1 = vn1; }
  }
  int b = bh / NH_, h = bh % NH_;
#pragma unroll
  for (int u = 0; u < 2; ++u) {
    float linv = 1.f / l_[u];
#pragma unroll
    for (int r = 0; r < 4; ++r) {
      float li = __shfl(linv, lg * 4 + r);
      int q = q0 + u * 16 + lg * 4 + r;
      obh[(size_t)(b * 1024 + q) * 96 + h * 16 + lr] = (_Float16)(O[u][r] * li);
    }
  }
}

extern "C" void kernel_launch(void* const* d_in, const int* in_sizes, int n_in,
                              void* d_out, int out_size, void* d_ws, size_t ws_size,
                              hipStream_t stream) {
  const float* goals   = (const float*)d_in[0];
  const float* obss    = (const float*)d_in[1];
  const float* w_go    = (const float*)d_in[2];
  const float* b_go    = (const float*)d_in[3];
  const float* pos_emb = (const float*)d_in[4];
  const float* wq      = (const float*)d_in[5];
  const float* wk      = (const float*)d_in[6];
  const float* wv      = (const float*)d_in[7];
  const float* w_proj  = (const float*)d_in[8];
  const float* b_proj  = (const float*)d_in[9];
  const float* ln1_g   = (const float*)d_in[10];
  const float* ln1_b   = (const float*)d_in[11];
  const float* ln2_g   = (const float*)d_in[12];
  const float* ln2_b   = (const float*)d_in[13];
  const float* w_ff1   = (const float*)d_in[14];
  const float* b_ff1   = (const float*)d_in[15];
  const float* w_ff2   = (const float*)d_in[16];
  const float* b_ff2   = (const float*)d_in[17];
  const float* lnf_g   = (const float*)d_in[18];
  const float* lnf_b   = (const float*)d_in[19];
  const float* w_act   = (const float*)d_in[20];
  const float* b_act   = (const float*)d_in[21];
  float* out = (float*)d_out;

  const int M = B_ * T_;  // 16384
  float* ws = (float*)d_ws;
  size_t off = 0;
  _Float16* P = (_Float16*)(ws + off); off += PACK_TOTAL / 2 + 64;
  _Float16* e0h = (_Float16*)(ws + off); off += (size_t)M * 48;
  float* x = ws + off; off += (size_t)M * 96;
  _Float16* obh = (_Float16*)(ws + off); off += (size_t)M * 48;
  _Float16* f1h = (_Float16*)(ws + off); off += (size_t)M * 192;
  _Float16* Qh = (_Float16*)(ws + off); off += (size_t)M * 48;
  _Float16* Kh = (_Float16*)(ws + off); off += (size_t)M * 48;
  _Float16* Vt = (_Float16*)(ws + off); off += (size_t)M * 48;

  pack_all_kernel<<<(PACK_TOTAL + 255) / 256, 256, 0, stream>>>(
      w_go, wq, wk, wv, w_proj, w_ff1, w_ff2, w_act, P);
  concat_kernel<<<(M * 96) / 256, 256, 0, stream>>>(goals, obss, e0h);
  // x = e0 @ w_go + b_go + pos
  gemm16<6, 6, false, EPI_POS><<<dim3(M / 64, 1), 256, 0, stream>>>(
      e0h, P + OFF_GO, b_go, nullptr, pos_emb, nullptr, nullptr, x, nullptr,
      nullptr, nullptr, nullptr, 96);
  for (int l = 0; l < L_; ++l) {
    gemm16<6, 6, true, EPI_QKV><<<dim3(M / 64, 3), 256, 0, stream>>>(
        x, P + OFF_QKV + (size_t)l * 27648, nullptr, nullptr, nullptr,
        ln1_g + l * 96, ln1_b + l * 96, nullptr, nullptr, Qh, Kh, Vt, 0);
    attn_mfma_kernel<<<dim3(B_ * NH_, 8), 256, 0, stream>>>(Qh, Kh, Vt, obh);
    gemm16<6, 6, false, EPI_RESID><<<dim3(M / 64, 1), 256, 0, stream>>>(
        obh, P + OFF_PROJ + (size_t)l * 9216, b_proj + l * 96, x, nullptr,
        nullptr, nullptr, x, nullptr, nullptr, nullptr, nullptr, 96);
    gemm16<6, 6, true, EPI_RELUH><<<dim3(M / 64, 4), 256, 0, stream>>>(
        x, P + OFF_FF1 + (size_t)l * 36864, b_ff1 + l * 384, nullptr, nullptr,
        ln2_g + l * 96, ln2_b + l * 96, nullptr, f1h, nullptr, nullptr, nullptr,
        384);
    gemm16<24, 6, false, EPI_RESID><<<dim3(M / 64, 1), 256, 0, stream>>>(
        f1h, P + OFF_FF2 + (size_t)l * 36864, b_ff2 + l * 96, x, nullptr,
        nullptr, nullptr, x, nullptr, nullptr, nullptr, nullptr, 96);
  }
  gemm16<6, 1, true, EPI_OUT><<<dim3(M / 64, 1), 256, 0, stream>>>(
      x, P + OFF_ACT, b_act, nullptr, nullptr, lnf_g, lnf_b, out, nullptr,
      nullptr, nullptr, nullptr, 16);
}

// Round 4
// 476.437 us; speedup vs baseline: 3.5124x; 1.1941x over previous
//
#include <hip/hip_runtime.h>
#include <math.h>

#define B_ 16
#define T_ 1024
#define D_ 96
#define L_ 6
#define NH_ 6
#define HS_ 16
#define FF_ 384

typedef _Float16 h4 __attribute__((ext_vector_type(4)));
typedef float f4 __attribute__((ext_vector_type(4)));

// packed f16 W^T buffer segment offsets (in halves)
#define OFF_GO   0
#define OFF_QKV  9216
#define OFF_PROJ 175104
#define OFF_FF1  230400
#define OFF_FF2  451584
#define OFF_ACT  672768
#define PACK_TOTAL 674304

enum { EPI_POS = 0, EPI_QKV = 1, EPI_OUT = 4 };

// ---------- pack all weights -> f16 W^T [N][K] ----------
__global__ __launch_bounds__(256) void pack_all_kernel(
    const float* __restrict__ w_go, const float* __restrict__ wq,
    const float* __restrict__ wk, const float* __restrict__ wv,
    const float* __restrict__ w_proj, const float* __restrict__ w_ff1,
    const float* __restrict__ w_ff2, const float* __restrict__ w_act,
    _Float16* __restrict__ P) {
  int i = blockIdx.x * 256 + threadIdx.x;
  if (i >= PACK_TOTAL) return;
  float v;
  if (i < OFF_QKV) {                       // w_go [96k][96n] -> [n][k]
    int o = i, n = o / 96, k = o % 96;
    v = w_go[k * 96 + n];
  } else if (i < OFF_PROJ) {               // wq/wk/wv -> [l][c][d]
    int o = i - OFF_QKV;
    int l = o / 27648, r = o % 27648, c = r / 96, d = r % 96;
    int which = c / 96;
    which = c / 96;
    int hc = c % 96, h = hc >> 4, j = hc & 15;
    const float* s = (which == 0) ? wq : (which == 1 ? wk : wv);
    v = s[((l * NH_ + h) * 96 + d) * 16 + j];
  } else if (i < OFF_FF1) {                // w_proj [l][96k][96n] -> [l][n][k]
    int o = i - OFF_PROJ;
    int l = o / 9216, r = o % 9216, n = r / 96, k = r % 96;
    v = w_proj[l * 9216 + k * 96 + n];
  } else if (i < OFF_FF2) {                // w_ff1 [l][96k][384n] -> [l][n][k]
    int o = i - OFF_FF1;
    int l = o / 36864, r = o % 36864, n = r / 96, k = r % 96;
    v = w_ff1[l * 36864 + k * 384 + n];
  } else if (i < OFF_ACT) {                // w_ff2 [l][384k][96n] -> [l][n][k]
    int o = i - OFF_FF2;
    int l = o / 36864, r = o % 36864, n = r / 384, k = r % 384;
    v = w_ff2[l * 36864 + k * 96 + n];
  } else {                                 // w_act [96k][16n] -> [n][k]
    int o = i - OFF_ACT;
    int n = o / 96, k = o % 96;
    v = w_act[k * 16 + n];
  }
  P[i] = (_Float16)v;
}

// ---------- concat(goals, obss) -> e0h [B*T, 96] f16 ----------
__global__ __launch_bounds__(256) void concat_kernel(
    const float* __restrict__ goals, const float* __restrict__ obss,
    _Float16* __restrict__ e0h) {
  int idx = blockIdx.x * 256 + threadIdx.x;
  int row = idx / 96;
  int d = idx % 96;
  int b = row >> 10;
  int t = row & 1023;
  float v;
  if (d < 32) v = goals[b * 32 + d];
  else        v = obss[(size_t)(b * 1024 + t) * 64 + (d - 32)];
  e0h[idx] = (_Float16)v;
}

// ---------- f16 MFMA GEMM (embed / qkv / head) ----------
template <int KSTEPS, int NFRAGS, bool LNF, int EPI>
__global__ __launch_bounds__(256) void gemm16(
    const void* __restrict__ Ain, const _Float16* __restrict__ Wt,
    const float* __restrict__ bias, const float* __restrict__ pos,
    const float* __restrict__ lng, const float* __restrict__ lnb,
    float* outf, _Float16* __restrict__ qh, _Float16* __restrict__ kh,
    _Float16* __restrict__ vt, int ldo) {
  constexpr int K = KSTEPS * 16;
  int tid = threadIdx.x;
  int wave = tid >> 6, lane = tid & 63;
  int lr = lane & 15, lg = lane >> 4;
  int row0 = blockIdx.x * 64 + wave * 16;
  int n0 = blockIdx.y * (NFRAGS * 16);
  int arow = row0 + lr;

  h4 af[KSTEPS];
  if constexpr (LNF) {
    static_assert(KSTEPS == 6, "LN fuse requires K=96");
    const float* xr = (const float*)Ain + (size_t)arow * 96 + lg * 4;
    float v[6][4];
    float s = 0.f, sq = 0.f;
#pragma unroll
    for (int st = 0; st < 6; ++st) {
      f4 t4 = *(const f4*)(xr + st * 16);
#pragma unroll
      for (int j = 0; j < 4; ++j) {
        v[st][j] = t4[j];
        s += t4[j];
        sq += t4[j] * t4[j];
      }
    }
    s += __shfl_xor(s, 16); sq += __shfl_xor(sq, 16);
    s += __shfl_xor(s, 32); sq += __shfl_xor(sq, 32);
    float mean = s * (1.f / 96.f);
    float rs = rsqrtf(sq * (1.f / 96.f) - mean * mean + 1e-5f);
#pragma unroll
    for (int st = 0; st < 6; ++st) {
      f4 g4 = *(const f4*)(lng + st * 16 + lg * 4);
      f4 b4 = *(const f4*)(lnb + st * 16 + lg * 4);
#pragma unroll
      for (int j = 0; j < 4; ++j)
        af[st][j] = (_Float16)((v[st][j] - mean) * rs * g4[j] + b4[j]);
    }
  } else {
    const _Float16* ar = (const _Float16*)Ain + (size_t)arow * K + lg * 4;
#pragma unroll
    for (int st = 0; st < KSTEPS; ++st)
      af[st] = *(const h4*)(ar + st * 16);
  }

  f4 acc[NFRAGS];
#pragma unroll
  for (int nf = 0; nf < NFRAGS; ++nf) acc[nf] = (f4){0.f, 0.f, 0.f, 0.f};

  const _Float16* wb = Wt + (size_t)(n0 + lr) * K + lg * 4;
#pragma unroll
  for (int st = 0; st < KSTEPS; ++st) {
#pragma unroll
    for (int nf = 0; nf < NFRAGS; ++nf) {
      h4 wf = *(const h4*)(wb + (size_t)nf * 16 * K + st * 16);
      acc[nf] = __builtin_amdgcn_mfma_f32_16x16x16f16(af[st], wf, acc[nf], 0, 0, 0);
    }
  }

  if constexpr (EPI == EPI_QKV) {
    int b = row0 >> 10;
    int t0 = row0 & 1023;
    int which = blockIdx.y;  // 0=Q, 1=K, 2=V
#pragma unroll
    for (int nf = 0; nf < NFRAGS; ++nf) {
      int bh = b * NH_ + nf;
      if (which < 2) {
        _Float16* dst = (which == 0 ? qh : kh) + (size_t)bh * 1024 * 16 + lr;
#pragma unroll
        for (int r = 0; r < 4; ++r)
          dst[(size_t)(t0 + lg * 4 + r) * 16] = (_Float16)acc[nf][r];
      } else {
        _Float16* dst = vt + (size_t)bh * 16 * 1024 + (size_t)lr * 1024 + t0 + lg * 4;
#pragma unroll
        for (int r = 0; r < 4; ++r) dst[r] = (_Float16)acc[nf][r];
      }
    }
  } else {
#pragma unroll
    for (int nf = 0; nf < NFRAGS; ++nf) {
      int col = n0 + nf * 16 + lr;
      float bb = bias[col];
#pragma unroll
      for (int r = 0; r < 4; ++r) {
        int row = row0 + lg * 4 + r;
        float vv = acc[nf][r] + bb;
        if constexpr (EPI == EPI_POS)
          vv += pos[(size_t)(row & 1023) * 96 + col];
        outf[(size_t)row * ldo + col] = vv;
      }
    }
  }
}

// ---------- fused MLP: proj + resid + LN2 + ff1 + ReLU + ff2 + resid --------
// All in transposed space; D-layout of each mfma feeds the next as B-frag.
// x updated in place (each lane owns its (row, col-chunk) slots exclusively).
__global__ __launch_bounds__(256) void mlp_fused_kernel(
    const _Float16* __restrict__ obh, float* __restrict__ x,
    const _Float16* __restrict__ Wp, const float* __restrict__ bp,
    const _Float16* __restrict__ W1, const float* __restrict__ b1,
    const _Float16* __restrict__ W2, const float* __restrict__ b2,
    const float* __restrict__ lng, const float* __restrict__ lnb) {
  int tid = threadIdx.x;
  int wave = tid >> 6, lane = tid & 63;
  int lr = lane & 15, lg = lane >> 4;
  int row0 = blockIdx.x * 64 + wave * 16;
  const f4 zero4 = {0.f, 0.f, 0.f, 0.f};

  // obh rows as B-frags (B[k=d][col=xr])
  h4 obf[6];
  const _Float16* orow = obh + (size_t)(row0 + lr) * 96 + lg * 4;
#pragma unroll
  for (int st = 0; st < 6; ++st) obf[st] = *(const h4*)(orow + st * 16);

  // proj^T + bias + resid -> x1 (lane holds x1[row0+lr][cf*16+lg*4+r])
  f4 x1[6];
#pragma unroll
  for (int cf = 0; cf < 6; ++cf) {
    f4 a = zero4;
    const _Float16* wrow = Wp + (size_t)(cf * 16 + lr) * 96 + lg * 4;
#pragma unroll
    for (int st = 0; st < 6; ++st) {
      h4 wf = *(const h4*)(wrow + st * 16);
      a = __builtin_amdgcn_mfma_f32_16x16x16f16(wf, obf[st], a, 0, 0, 0);
    }
    f4 bb = *(const f4*)(bp + cf * 16 + lg * 4);
    f4 xr4 = *(const f4*)(x + (size_t)(row0 + lr) * 96 + cf * 16 + lg * 4);
#pragma unroll
    for (int j = 0; j < 4; ++j) x1[cf][j] = a[j] + bb[j] + xr4[j];
  }

  // LN2 (row values lane-local: 24 per lane, reduce over lg)
  float s = 0.f, sq = 0.f;
#pragma unroll
  for (int cf = 0; cf < 6; ++cf)
#pragma unroll
    for (int j = 0; j < 4; ++j) { s += x1[cf][j]; sq += x1[cf][j] * x1[cf][j]; }
  s += __shfl_xor(s, 16); sq += __shfl_xor(sq, 16);
  s += __shfl_xor(s, 32); sq += __shfl_xor(sq, 32);
  float mean = s * (1.f / 96.f);
  float rs = rsqrtf(sq * (1.f / 96.f) - mean * mean + 1e-5f);
  h4 xnf[6];
#pragma unroll
  for (int cf = 0; cf < 6; ++cf) {
    f4 g4 = *(const f4*)(lng + cf * 16 + lg * 4);
    f4 b4 = *(const f4*)(lnb + cf * 16 + lg * 4);
#pragma unroll
    for (int j = 0; j < 4; ++j)
      xnf[cf][j] = (_Float16)((x1[cf][j] - mean) * rs * g4[j] + b4[j]);
  }

  // ff1 + bias + ReLU -> H^T frags (reused directly as ff2 B-frags)
  h4 hf[24];
#pragma unroll
  for (int nf = 0; nf < 24; ++nf) {
    f4 h = zero4;
    const _Float16* wrow = W1 + (size_t)(nf * 16 + lr) * 96 + lg * 4;
#pragma unroll
    for (int st = 0; st < 6; ++st) {
      h4 wf = *(const h4*)(wrow + st * 16);
      h = __builtin_amdgcn_mfma_f32_16x16x16f16(wf, xnf[st], h, 0, 0, 0);
    }
    f4 bb = *(const f4*)(b1 + nf * 16 + lg * 4);
#pragma unroll
    for (int j = 0; j < 4; ++j)
      hf[nf][j] = (_Float16)fmaxf(h[j] + bb[j], 0.f);
  }

  // ff2 + bias + resid -> write x
#pragma unroll
  for (int mf = 0; mf < 6; ++mf) {
    f4 y = zero4;
    const _Float16* wrow = W2 + (size_t)(mf * 16 + lr) * 384 + lg * 4;
#pragma unroll
    for (int nf = 0; nf < 24; ++nf) {
      h4 wf = *(const h4*)(wrow + nf * 16);
      y = __builtin_amdgcn_mfma_f32_16x16x16f16(wf, hf[nf], y, 0, 0, 0);
    }
    f4 bb = *(const f4*)(b2 + mf * 16 + lg * 4);
    f4 o;
#pragma unroll
    for (int j = 0; j < 4; ++j) o[j] = x1[mf][j] + y[j] + bb[j];
    *(f4*)(x + (size_t)(row0 + lr) * 96 + mf * 16 + lg * 4) = o;
  }
}

// ---------- MFMA f16 flash attention ----------
__global__ __launch_bounds__(256) void attn_mfma_kernel(
    const _Float16* __restrict__ Qh, const _Float16* __restrict__ Kh,
    const _Float16* __restrict__ Vt, _Float16* __restrict__ obh) {
  int bh = blockIdx.x;
  int wave = threadIdx.x >> 6;
  int lane = threadIdx.x & 63;
  int qt = wave * 8 + blockIdx.y;
  int q0 = qt * 32;
  int lr = lane & 15;
  int lg = lane >> 4;

  const _Float16* qb = Qh + (size_t)bh * 1024 * 16;
  const _Float16* kb = Kh + (size_t)bh * 1024 * 16;
  const _Float16* vb = Vt + (size_t)bh * 16 * 1024;

  h4 qf[2];
#pragma unroll
  for (int u = 0; u < 2; ++u) {
    h4 qv = *(const h4*)(qb + (size_t)(q0 + u * 16 + lr) * 16 + lg * 4);
#pragma unroll
    for (int j = 0; j < 4; ++j) qv[j] = qv[j] * (_Float16)0.25f;
    qf[u] = qv;
  }

  f4 O[2] = {{0.f, 0.f, 0.f, 0.f}, {0.f, 0.f, 0.f, 0.f}};
  float m_[2] = {-1e30f, -1e30f};
  float l_[2] = {0.f, 0.f};
  const f4 zero4 = {0.f, 0.f, 0.f, 0.f};

  int ntiles = qt + 1;
  h4 kc0, kc1, vc0, vc1, kn0, kn1, vn0, vn1;
  kc0 = *(const h4*)(kb + (size_t)lr * 16 + lg * 4);
  kc1 = *(const h4*)(kb + (size_t)(16 + lr) * 16 + lg * 4);
  vc0 = *(const h4*)(vb + (size_t)lr * 1024 + lg * 4);
  vc1 = *(const h4*)(vb + (size_t)lr * 1024 + 16 + lg * 4);

  for (int tt = 0; tt < ntiles; ++tt) {
    int s0 = tt * 32;
    bool last = (tt == ntiles - 1);
    if (!last) {
      int s1 = s0 + 32;
      kn0 = *(const h4*)(kb + (size_t)(s1 + lr) * 16 + lg * 4);
      kn1 = *(const h4*)(kb + (size_t)(s1 + 16 + lr) * 16 + lg * 4);
      vn0 = *(const h4*)(vb + (size_t)lr * 1024 + s1 + lg * 4);
      vn1 = *(const h4*)(vb + (size_t)lr * 1024 + s1 + 16 + lg * 4);
    }
#pragma unroll
    for (int u = 0; u < 2; ++u) {
      int qu = q0 + u * 16;
      bool act1 = (s0 + 16 <= qu + 15);
      f4 st0 = __builtin_amdgcn_mfma_f32_16x16x16f16(kc0, qf[u], zero4, 0, 0, 0);
      f4 st1;
      if (act1)
        st1 = __builtin_amdgcn_mfma_f32_16x16x16f16(kc1, qf[u], zero4, 0, 0, 0);
      else
        st1 = (f4){-1e30f, -1e30f, -1e30f, -1e30f};
      if (last) {
        int qidx = qu + lr;
#pragma unroll
        for (int r = 0; r < 4; ++r) {
          if (s0 + lg * 4 + r > qidx) st0[r] = -1e30f;
          if (s0 + 16 + lg * 4 + r > qidx) st1[r] = -1e30f;
        }
      }
      float mx = fmaxf(fmaxf(fmaxf(st0[0], st0[1]), fmaxf(st0[2], st0[3])),
                       fmaxf(fmaxf(st1[0], st1[1]), fmaxf(st1[2], st1[3])));
      mx = fmaxf(mx, __shfl_xor(mx, 16));
      mx = fmaxf(mx, __shfl_xor(mx, 32));
      float mn = fmaxf(m_[u], mx);
      bool norescale = (mn == m_[u]);
      float corr = norescale ? 1.f : __expf(m_[u] - mn);
      m_[u] = mn;
      float p0[4], p1[4];
      float ps = 0.f;
#pragma unroll
      for (int r = 0; r < 4; ++r) { p0[r] = __expf(st0[r] - mn); ps += p0[r]; }
      if (act1) {
#pragma unroll
        for (int r = 0; r < 4; ++r) { p1[r] = __expf(st1[r] - mn); ps += p1[r]; }
      }
      ps += __shfl_xor(ps, 16);
      ps += __shfl_xor(ps, 32);
      l_[u] = l_[u] * corr + ps;
      if (!__all(norescale)) {
#pragma unroll
        for (int r = 0; r < 4; ++r) {
          float c = __shfl(corr, lg * 4 + r);
          O[u][r] *= c;
        }
      }
      h4 pf0 = {(_Float16)p0[0], (_Float16)p0[1], (_Float16)p0[2], (_Float16)p0[3]};
      O[u] = __builtin_amdgcn_mfma_f32_16x16x16f16(pf0, vc0, O[u], 0, 0, 0);
      if (act1) {
        h4 pf1 = {(_Float16)p1[0], (_Float16)p1[1], (_Float16)p1[2], (_Float16)p1[3]};
        O[u] = __builtin_amdgcn_mfma_f32_16x16x16f16(pf1, vc1, O[u], 0, 0, 0);
      }
    }
    if (!last) { kc0 = kn0; kc1 = kn1; vc0 = vn0; vc1 = vn1; }
  }
  int b = bh / NH_, h = bh % NH_;
#pragma unroll
  for (int u = 0; u < 2; ++u) {
    float linv = 1.f / l_[u];
#pragma unroll
    for (int r = 0; r < 4; ++r) {
      float li = __shfl(linv, lg * 4 + r);
      int q = q0 + u * 16 + lg * 4 + r;
      obh[(size_t)(b * 1024 + q) * 96 + h * 16 + lr] = (_Float16)(O[u][r] * li);
    }
  }
}

extern "C" void kernel_launch(void* const* d_in, const int* in_sizes, int n_in,
                              void* d_out, int out_size, void* d_ws, size_t ws_size,
                              hipStream_t stream) {
  const float* goals   = (const float*)d_in[0];
  const float* obss    = (const float*)d_in[1];
  const float* w_go    = (const float*)d_in[2];
  const float* b_go    = (const float*)d_in[3];
  const float* pos_emb = (const float*)d_in[4];
  const float* wq      = (const float*)d_in[5];
  const float* wk      = (const float*)d_in[6];
  const float* wv      = (const float*)d_in[7];
  const float* w_proj  = (const float*)d_in[8];
  const float* b_proj  = (const float*)d_in[9];
  const float* ln1_g   = (const float*)d_in[10];
  const float* ln1_b   = (const float*)d_in[11];
  const float* ln2_g   = (const float*)d_in[12];
  const float* ln2_b   = (const float*)d_in[13];
  const float* w_ff1   = (const float*)d_in[14];
  const float* b_ff1   = (const float*)d_in[15];
  const float* w_ff2   = (const float*)d_in[16];
  const float* b_ff2   = (const float*)d_in[17];
  const float* lnf_g   = (const float*)d_in[18];
  const float* lnf_b   = (const float*)d_in[19];
  const float* w_act   = (const float*)d_in[20];
  const float* b_act   = (const float*)d_in[21];
  float* out = (float*)d_out;

  const int M = B_ * T_;  // 16384
  float* ws = (float*)d_ws;
  size_t off = 0;
  _Float16* P = (_Float16*)(ws + off); off += PACK_TOTAL / 2 + 64;
  _Float16* e0h = (_Float16*)(ws + off); off += (size_t)M * 48;
  float* x = ws + off; off += (size_t)M * 96;
  _Float16* obh = (_Float16*)(ws + off); off += (size_t)M * 48;
  _Float16* Qh = (_Float16*)(ws + off); off += (size_t)M * 48;
  _Float16* Kh = (_Float16*)(ws + off); off += (size_t)M * 48;
  _Float16* Vt = (_Float16*)(ws + off); off += (size_t)M * 48;

  pack_all_kernel<<<(PACK_TOTAL + 255) / 256, 256, 0, stream>>>(
      w_go, wq, wk, wv, w_proj, w_ff1, w_ff2, w_act, P);
  concat_kernel<<<(M * 96) / 256, 256, 0, stream>>>(goals, obss, e0h);
  gemm16<6, 6, false, EPI_POS><<<dim3(M / 64, 1), 256, 0, stream>>>(
      e0h, P + OFF_GO, b_go, pos_emb, nullptr, nullptr, x,
      nullptr, nullptr, nullptr, 96);
  for (int l = 0; l < L_; ++l) {
    gemm16<6, 6, true, EPI_QKV><<<dim3(M / 64, 3), 256, 0, stream>>>(
        x, P + OFF_QKV + (size_t)l * 27648, nullptr, nullptr,
        ln1_g + l * 96, ln1_b + l * 96, nullptr, Qh, Kh, Vt, 0);
    attn_mfma_kernel<<<dim3(B_ * NH_, 8), 256, 0, stream>>>(Qh, Kh, Vt, obh);
    mlp_fused_kernel<<<M / 64, 256, 0, stream>>>(
        obh, x,
        P + OFF_PROJ + (size_t)l * 9216, b_proj + l * 96,
        P + OFF_FF1 + (size_t)l * 36864, b_ff1 + l * 384,
        P + OFF_FF2 + (size_t)l * 36864, b_ff2 + l * 96,
        ln2_g + l * 96, ln2_b + l * 96);
  }
  gemm16<6, 1, true, EPI_OUT><<<dim3(M / 64, 1), 256, 0, stream>>>(
      x, P + OFF_ACT, b_act, nullptr, lnf_g, lnf_b, out,
      nullptr, nullptr, nullptr, 16);
}

// Round 5
// 449.829 us; speedup vs baseline: 3.7201x; 1.0591x over previous
//
#include <hip/hip_runtime.h>
#include <math.h>

#define B_ 16
#define T_ 1024
#define D_ 96
#define L_ 6
#define NH_ 6
#define HS_ 16
#define FF_ 384

typedef _Float16 h4 __attribute__((ext_vector_type(4)));
typedef float f4 __attribute__((ext_vector_type(4)));

// packed f16 W^T buffer segment offsets (in halves)
#define OFF_GO   0
#define OFF_QKV  9216
#define OFF_PROJ 175104
#define OFF_FF1  230400
#define OFF_FF2  451584
#define OFF_ACT  672768
#define PACK_TOTAL 674304

// Q weights pre-scaled by 1/sqrt(16) * log2(e) so attn uses exp2 directly.
#define QSCALE 0.3606737602222409f

// ---------- pack all weights -> f16 W^T [N][K] ----------
__global__ __launch_bounds__(256) void pack_all_kernel(
    const float* __restrict__ w_go, const float* __restrict__ wq,
    const float* __restrict__ wk, const float* __restrict__ wv,
    const float* __restrict__ w_proj, const float* __restrict__ w_ff1,
    const float* __restrict__ w_ff2, const float* __restrict__ w_act,
    _Float16* __restrict__ P) {
  int i = blockIdx.x * 256 + threadIdx.x;
  if (i >= PACK_TOTAL) return;
  float v;
  if (i < OFF_QKV) {                       // w_go [96k][96n] -> [n][k]
    int o = i, n = o / 96, k = o % 96;
    v = w_go[k * 96 + n];
  } else if (i < OFF_PROJ) {               // wq/wk/wv -> [l][c=288][d=96]
    int o = i - OFF_QKV;
    int l = o / 27648, r = o % 27648, c = r / 96, d = r % 96;
    int which = c / 96;
    int hc = c % 96, h = hc >> 4, j = hc & 15;
    const float* s = (which == 0) ? wq : (which == 1 ? wk : wv);
    v = s[((l * NH_ + h) * 96 + d) * 16 + j];
    if (which == 0) v *= QSCALE;
  } else if (i < OFF_FF1) {                // w_proj [l][96k][96n] -> [l][n][k]
    int o = i - OFF_PROJ;
    int l = o / 9216, r = o % 9216, n = r / 96, k = r % 96;
    v = w_proj[l * 9216 + k * 96 + n];
  } else if (i < OFF_FF2) {                // w_ff1 [l][96k][384n] -> [l][n][k]
    int o = i - OFF_FF1;
    int l = o / 36864, r = o % 36864, n = r / 96, k = r % 96;
    v = w_ff1[l * 36864 + k * 384 + n];
  } else if (i < OFF_ACT) {                // w_ff2 [l][384k][96n] -> [l][n][k]
    int o = i - OFF_FF2;
    int l = o / 36864, r = o % 36864, n = r / 384, k = r % 384;
    v = w_ff2[l * 36864 + k * 96 + n];
  } else {                                 // w_act [96k][16n] -> [n][k]
    int o = i - OFF_ACT;
    int n = o / 96, k = o % 96;
    v = w_act[k * 16 + n];
  }
  P[i] = (_Float16)v;
}

// ---------- fused stage kernel ----------
// EMBED: x1 = concat(goals,obss) @ w_go + b_go + pos; write x; tail on x1.
// else : x1 = x + proj(obh) + bp; x2 = x1 + ff2(relu(ff1(LN2(x1)))) + b2;
//        write x (unless HEAD); tail on x2.
// tail: HEAD ? out = LN_f(xc) @ w_act + b_act  :  qkv = LN1(xc) @ Wqkv.
// All in transposed MFMA space; lane holds val[token=row0+lr][col=cf*16+lg*4+j].
template <bool EMBED, bool HEAD>
__global__ __launch_bounds__(256, 1) void stage_kernel(
    const float* __restrict__ goals, const float* __restrict__ obss,
    const float* __restrict__ pos, const float* __restrict__ b_go,
    const _Float16* __restrict__ obh, const _Float16* __restrict__ Wp,
    const float* __restrict__ bp, float* __restrict__ x,
    const _Float16* __restrict__ W1, const float* __restrict__ b1,
    const _Float16* __restrict__ W2, const float* __restrict__ b2,
    const float* __restrict__ ln2g, const float* __restrict__ ln2b,
    const float* __restrict__ lntg, const float* __restrict__ lntb,
    const _Float16* __restrict__ Wtail, const float* __restrict__ btail,
    _Float16* __restrict__ qh, _Float16* __restrict__ kh,
    _Float16* __restrict__ vt, float* __restrict__ out) {
  int tid = threadIdx.x;
  int wave = tid >> 6, lane = tid & 63;
  int lr = lane & 15, lg = lane >> 4;
  int row0 = blockIdx.x * 64 + wave * 16;
  int token = row0 + lr;
  const f4 zero4 = {0.f, 0.f, 0.f, 0.f};

  f4 xc[6];  // current residual value per lane chunk
  if constexpr (EMBED) {
    int b = token >> 10, t = token & 1023;
    h4 ef[6];
#pragma unroll
    for (int st = 0; st < 6; ++st) {
      int k0 = st * 16 + lg * 4;
      f4 s4;
      if (st < 2) s4 = *(const f4*)(goals + b * 32 + k0);
      else        s4 = *(const f4*)(obss + (size_t)(b * 1024 + t) * 64 + (k0 - 32));
      ef[st] = (h4){(_Float16)s4[0], (_Float16)s4[1], (_Float16)s4[2], (_Float16)s4[3]};
    }
#pragma unroll
    for (int cf = 0; cf < 6; ++cf) {
      f4 a = zero4;
      const _Float16* wrow = Wp + (size_t)(cf * 16 + lr) * 96 + lg * 4;
#pragma unroll
      for (int st = 0; st < 6; ++st) {
        h4 wf = *(const h4*)(wrow + st * 16);
        a = __builtin_amdgcn_mfma_f32_16x16x16f16(wf, ef[st], a, 0, 0, 0);
      }
      f4 bb = *(const f4*)(b_go + cf * 16 + lg * 4);
      f4 pp = *(const f4*)(pos + (size_t)t * 96 + cf * 16 + lg * 4);
#pragma unroll
      for (int j = 0; j < 4; ++j) xc[cf][j] = a[j] + bb[j] + pp[j];
      *(f4*)(x + (size_t)token * 96 + cf * 16 + lg * 4) = xc[cf];
    }
  } else {
    // proj + resid
    h4 obf[6];
    const _Float16* orow = obh + (size_t)token * 96 + lg * 4;
#pragma unroll
    for (int st = 0; st < 6; ++st) obf[st] = *(const h4*)(orow + st * 16);
    f4 x1[6];
#pragma unroll
    for (int cf = 0; cf < 6; ++cf) {
      f4 a = zero4;
      const _Float16* wrow = Wp + (size_t)(cf * 16 + lr) * 96 + lg * 4;
#pragma unroll
      for (int st = 0; st < 6; ++st) {
        h4 wf = *(const h4*)(wrow + st * 16);
        a = __builtin_amdgcn_mfma_f32_16x16x16f16(wf, obf[st], a, 0, 0, 0);
      }
      f4 bb = *(const f4*)(bp + cf * 16 + lg * 4);
      f4 xr4 = *(const f4*)(x + (size_t)token * 96 + cf * 16 + lg * 4);
#pragma unroll
      for (int j = 0; j < 4; ++j) x1[cf][j] = a[j] + bb[j] + xr4[j];
    }
    // LN2
    float s = 0.f, sq = 0.f;
#pragma unroll
    for (int cf = 0; cf < 6; ++cf)
#pragma unroll
      for (int j = 0; j < 4; ++j) { s += x1[cf][j]; sq += x1[cf][j] * x1[cf][j]; }
    s += __shfl_xor(s, 16); sq += __shfl_xor(sq, 16);
    s += __shfl_xor(s, 32); sq += __shfl_xor(sq, 32);
    float mean = s * (1.f / 96.f);
    float rs = rsqrtf(sq * (1.f / 96.f) - mean * mean + 1e-5f);
    h4 xnf[6];
#pragma unroll
    for (int cf = 0; cf < 6; ++cf) {
      f4 g4 = *(const f4*)(ln2g + cf * 16 + lg * 4);
      f4 b4 = *(const f4*)(ln2b + cf * 16 + lg * 4);
#pragma unroll
      for (int j = 0; j < 4; ++j)
        xnf[cf][j] = (_Float16)((x1[cf][j] - mean) * rs * g4[j] + b4[j]);
    }
    // ff1 + relu
    h4 hf[24];
#pragma unroll
    for (int nf = 0; nf < 24; ++nf) {
      f4 h = zero4;
      const _Float16* wrow = W1 + (size_t)(nf * 16 + lr) * 96 + lg * 4;
#pragma unroll
      for (int st = 0; st < 6; ++st) {
        h4 wf = *(const h4*)(wrow + st * 16);
        h = __builtin_amdgcn_mfma_f32_16x16x16f16(wf, xnf[st], h, 0, 0, 0);
      }
      f4 bb = *(const f4*)(b1 + nf * 16 + lg * 4);
#pragma unroll
      for (int j = 0; j < 4; ++j)
        hf[nf][j] = (_Float16)fmaxf(h[j] + bb[j], 0.f);
    }
    // ff2 + resid -> xc
#pragma unroll
    for (int mf = 0; mf < 6; ++mf) {
      f4 y = zero4;
      const _Float16* wrow = W2 + (size_t)(mf * 16 + lr) * 384 + lg * 4;
#pragma unroll
      for (int nf = 0; nf < 24; ++nf) {
        h4 wf = *(const h4*)(wrow + nf * 16);
        y = __builtin_amdgcn_mfma_f32_16x16x16f16(wf, hf[nf], y, 0, 0, 0);
      }
      f4 bb = *(const f4*)(b2 + mf * 16 + lg * 4);
#pragma unroll
      for (int j = 0; j < 4; ++j) xc[mf][j] = x1[mf][j] + y[j] + bb[j];
      if constexpr (!HEAD)
        *(f4*)(x + (size_t)token * 96 + mf * 16 + lg * 4) = xc[mf];
    }
  }

  // ---- tail: LN(xc) ----
  {
    float s = 0.f, sq = 0.f;
#pragma unroll
    for (int cf = 0; cf < 6; ++cf)
#pragma unroll
      for (int j = 0; j < 4; ++j) { s += xc[cf][j]; sq += xc[cf][j] * xc[cf][j]; }
    s += __shfl_xor(s, 16); sq += __shfl_xor(sq, 16);
    s += __shfl_xor(s, 32); sq += __shfl_xor(sq, 32);
    float mean = s * (1.f / 96.f);
    float rs = rsqrtf(sq * (1.f / 96.f) - mean * mean + 1e-5f);
    h4 xnf[6];
#pragma unroll
    for (int cf = 0; cf < 6; ++cf) {
      f4 g4 = *(const f4*)(lntg + cf * 16 + lg * 4);
      f4 b4 = *(const f4*)(lntb + cf * 16 + lg * 4);
#pragma unroll
      for (int j = 0; j < 4; ++j)
        xnf[cf][j] = (_Float16)((xc[cf][j] - mean) * rs * g4[j] + b4[j]);
    }
    if constexpr (HEAD) {
      f4 a = zero4;
      const _Float16* wrow = Wtail + (size_t)lr * 96 + lg * 4;
#pragma unroll
      for (int st = 0; st < 6; ++st) {
        h4 wf = *(const h4*)(wrow + st * 16);
        a = __builtin_amdgcn_mfma_f32_16x16x16f16(wf, xnf[st], a, 0, 0, 0);
      }
      f4 bb = *(const f4*)(btail + lg * 4);
      f4 o;
#pragma unroll
      for (int j = 0; j < 4; ++j) o[j] = a[j] + bb[j];
      *(f4*)(out + (size_t)token * 16 + lg * 4) = o;
    } else {
      int b = token >> 10, t = token & 1023;
#pragma unroll
      for (int nf = 0; nf < 18; ++nf) {
        f4 a = zero4;
        const _Float16* wrow = Wtail + (size_t)(nf * 16 + lr) * 96 + lg * 4;
#pragma unroll
        for (int st = 0; st < 6; ++st) {
          h4 wf = *(const h4*)(wrow + st * 16);
          a = __builtin_amdgcn_mfma_f32_16x16x16f16(wf, xnf[st], a, 0, 0, 0);
        }
        // lane holds col n = nf*16+lg*4+r of token
        if (nf < 12) {  // Q (nf<6) / K (6..11): [bh][t][16]
          _Float16* dst = (nf < 6 ? qh : kh) +
                          (size_t)(b * NH_ + (nf % 6)) * 16384 + (size_t)t * 16 + lg * 4;
          h4 hv = {(_Float16)a[0], (_Float16)a[1], (_Float16)a[2], (_Float16)a[3]};
          *(h4*)dst = hv;
        } else {        // V: [bh][d][1024]
          _Float16* dst = vt + (size_t)(b * NH_ + (nf - 12)) * 16384 +
                          (size_t)(lg * 4) * 1024 + t;
#pragma unroll
          for (int r = 0; r < 4; ++r) dst[(size_t)r * 1024] = (_Float16)a[r];
        }
      }
    }
  }
}

// ---------- MFMA f16 flash attention, fixed-max softmax, 16-row waves ------
// Qh pre-scaled so p = exp2(S). grid (96 bh, 16), wave qt = wave*16+by in [0,64).
__global__ __launch_bounds__(256, 6) void attn_mfma_kernel(
    const _Float16* __restrict__ Qh, const _Float16* __restrict__ Kh,
    const _Float16* __restrict__ Vt, _Float16* __restrict__ obh) {
  int bh = blockIdx.x;
  int wave = threadIdx.x >> 6;
  int lane = threadIdx.x & 63;
  int qt = wave * 16 + blockIdx.y;   // 0..63
  int q0 = qt * 16;
  int lr = lane & 15;
  int lg = lane >> 4;

  const _Float16* qb = Qh + (size_t)bh * 16384;
  const _Float16* kb = Kh + (size_t)bh * 16384;
  const _Float16* vb = Vt + (size_t)bh * 16384;

  h4 qf = *(const h4*)(qb + (size_t)(q0 + lr) * 16 + lg * 4);
  f4 O = {0.f, 0.f, 0.f, 0.f};
  float lsum = 0.f;
  const f4 zero4 = {0.f, 0.f, 0.f, 0.f};

  int ntiles = qt / 2 + 1;
  h4 kc0, kc1, vc0, vc1, kn0, kn1, vn0, vn1;
  kc0 = *(const h4*)(kb + (size_t)lr * 16 + lg * 4);
  kc1 = *(const h4*)(kb + (size_t)(16 + lr) * 16 + lg * 4);
  vc0 = *(const h4*)(vb + (size_t)lr * 1024 + lg * 4);
  vc1 = *(const h4*)(vb + (size_t)lr * 1024 + 16 + lg * 4);

  for (int tt = 0; tt < ntiles; ++tt) {
    int s0 = tt * 32;
    bool last = (tt == ntiles - 1);
    if (!last) {
      int s1 = s0 + 32;
      kn0 = *(const h4*)(kb + (size_t)(s1 + lr) * 16 + lg * 4);
      kn1 = *(const h4*)(kb + (size_t)(s1 + 16 + lr) * 16 + lg * 4);
      vn0 = *(const h4*)(vb + (size_t)lr * 1024 + s1 + lg * 4);
      vn1 = *(const h4*)(vb + (size_t)lr * 1024 + s1 + 16 + lg * 4);
    }
    bool act1 = (s0 + 16 <= q0 + 15);
    // lane: S[q=q0+lr][s=s0(+16)+lg*4+r]
    f4 st0 = __builtin_amdgcn_mfma_f32_16x16x16f16(kc0, qf, zero4, 0, 0, 0);
    if (last) {
      int qi = q0 + lr;
#pragma unroll
      for (int r = 0; r < 4; ++r)
        if (s0 + lg * 4 + r > qi) st0[r] = -1e30f;
    }
    float p0[4];
#pragma unroll
    for (int r = 0; r < 4; ++r) {
      p0[r] = __builtin_amdgcn_exp2f(st0[r]);
      lsum += p0[r];
    }
    h4 pf0 = {(_Float16)p0[0], (_Float16)p0[1], (_Float16)p0[2], (_Float16)p0[3]};
    O = __builtin_amdgcn_mfma_f32_16x16x16f16(pf0, vc0, O, 0, 0, 0);
    if (act1) {
      f4 st1 = __builtin_amdgcn_mfma_f32_16x16x16f16(kc1, qf, zero4, 0, 0, 0);
      if (last) {
        int qi = q0 + lr;
#pragma unroll
        for (int r = 0; r < 4; ++r)
          if (s0 + 16 + lg * 4 + r > qi) st1[r] = -1e30f;
      }
      float p1[4];
#pragma unroll
      for (int r = 0; r < 4; ++r) {
        p1[r] = __builtin_amdgcn_exp2f(st1[r]);
        lsum += p1[r];
      }
      h4 pf1 = {(_Float16)p1[0], (_Float16)p1[1], (_Float16)p1[2], (_Float16)p1[3]};
      O = __builtin_amdgcn_mfma_f32_16x16x16f16(pf1, vc1, O, 0, 0, 0);
    }
    if (!last) { kc0 = kn0; kc1 = kn1; vc0 = vn0; vc1 = vn1; }
  }
  // reduce l over lane groups (lsum partial for q=q0+lr)
  lsum += __shfl_xor(lsum, 16);
  lsum += __shfl_xor(lsum, 32);
  float linv = 1.f / lsum;
  int b = bh / NH_, h = bh % NH_;
#pragma unroll
  for (int r = 0; r < 4; ++r) {
    float li = __shfl(linv, lg * 4 + r);
    int q = q0 + lg * 4 + r;
    obh[(size_t)(b * 1024 + q) * 96 + h * 16 + lr] = (_Float16)(O[r] * li);
  }
}

extern "C" void kernel_launch(void* const* d_in, const int* in_sizes, int n_in,
                              void* d_out, int out_size, void* d_ws, size_t ws_size,
                              hipStream_t stream) {
  const float* goals   = (const float*)d_in[0];
  const float* obss    = (const float*)d_in[1];
  const float* w_go    = (const float*)d_in[2];
  const float* b_go    = (const float*)d_in[3];
  const float* pos_emb = (const float*)d_in[4];
  const float* wq      = (const float*)d_in[5];
  const float* wk      = (const float*)d_in[6];
  const float* wv      = (const float*)d_in[7];
  const float* w_proj  = (const float*)d_in[8];
  const float* b_proj  = (const float*)d_in[9];
  const float* ln1_g   = (const float*)d_in[10];
  const float* ln1_b   = (const float*)d_in[11];
  const float* ln2_g   = (const float*)d_in[12];
  const float* ln2_b   = (const float*)d_in[13];
  const float* w_ff1   = (const float*)d_in[14];
  const float* b_ff1   = (const float*)d_in[15];
  const float* w_ff2   = (const float*)d_in[16];
  const float* b_ff2   = (const float*)d_in[17];
  const float* lnf_g   = (const float*)d_in[18];
  const float* lnf_b   = (const float*)d_in[19];
  const float* w_act   = (const float*)d_in[20];
  const float* b_act   = (const float*)d_in[21];
  float* out = (float*)d_out;

  const int M = B_ * T_;  // 16384
  float* ws = (float*)d_ws;
  size_t off = 0;
  _Float16* P = (_Float16*)(ws + off); off += PACK_TOTAL / 2 + 64;
  float* x = ws + off; off += (size_t)M * 96;
  _Float16* obh = (_Float16*)(ws + off); off += (size_t)M * 48;
  _Float16* Qh = (_Float16*)(ws + off); off += (size_t)M * 48;
  _Float16* Kh = (_Float16*)(ws + off); off += (size_t)M * 48;
  _Float16* Vt = (_Float16*)(ws + off); off += (size_t)M * 48;

  pack_all_kernel<<<(PACK_TOTAL + 255) / 256, 256, 0, stream>>>(
      w_go, wq, wk, wv, w_proj, w_ff1, w_ff2, w_act, P);

  // embed + qkv(layer 0)
  stage_kernel<true, false><<<M / 64, 256, 0, stream>>>(
      goals, obss, pos_emb, b_go, nullptr, P + OFF_GO, nullptr, x,
      nullptr, nullptr, nullptr, nullptr, nullptr, nullptr,
      ln1_g, ln1_b, P + OFF_QKV, nullptr, Qh, Kh, Vt, nullptr);

  for (int l = 0; l < L_; ++l) {
    attn_mfma_kernel<<<dim3(B_ * NH_, 16), 256, 0, stream>>>(Qh, Kh, Vt, obh);
    if (l < L_ - 1) {
      stage_kernel<false, false><<<M / 64, 256, 0, stream>>>(
          nullptr, nullptr, nullptr, nullptr, obh,
          P + OFF_PROJ + (size_t)l * 9216, b_proj + l * 96, x,
          P + OFF_FF1 + (size_t)l * 36864, b_ff1 + l * 384,
          P + OFF_FF2 + (size_t)l * 36864, b_ff2 + l * 96,
          ln2_g + l * 96, ln2_b + l * 96,
          ln1_g + (l + 1) * 96, ln1_b + (l + 1) * 96,
          P + OFF_QKV + (size_t)(l + 1) * 27648, nullptr, Qh, Kh, Vt, nullptr);
    } else {
      stage_kernel<false, true><<<M / 64, 256, 0, stream>>>(
          nullptr, nullptr, nullptr, nullptr, obh,
          P + OFF_PROJ + (size_t)l * 9216, b_proj + l * 96, x,
          P + OFF_FF1 + (size_t)l * 36864, b_ff1 + l * 384,
          P + OFF_FF2 + (size_t)l * 36864, b_ff2 + l * 96,
          ln2_g + l * 96, ln2_b + l * 96,
          lnf_g, lnf_b, P + OFF_ACT, b_act, nullptr, nullptr, nullptr, out);
    }
  }
}

// Round 6
// 446.855 us; speedup vs baseline: 3.7449x; 1.0067x over previous
//
#include <hip/hip_runtime.h>
#include <math.h>

#define B_ 16
#define T_ 1024
#define D_ 96
#define L_ 6
#define NH_ 6
#define HS_ 16
#define FF_ 384

typedef _Float16 h4 __attribute__((ext_vector_type(4)));
typedef float f4 __attribute__((ext_vector_type(4)));

// packed f16 W^T buffer segment offsets (in halves)
#define OFF_GO   0
#define OFF_QKV  9216
#define OFF_PROJ 175104
#define OFF_FF1  230400
#define OFF_FF2  451584
#define OFF_ACT  672768
#define PACK_TOTAL 674304

// Q weights pre-scaled by 1/sqrt(16) * log2(e) so attn uses exp2 directly.
#define QSCALE 0.3606737602222409f

// ---------- pack all weights -> f16 W^T [N][K] ----------
__global__ __launch_bounds__(256) void pack_all_kernel(
    const float* __restrict__ w_go, const float* __restrict__ wq,
    const float* __restrict__ wk, const float* __restrict__ wv,
    const float* __restrict__ w_proj, const float* __restrict__ w_ff1,
    const float* __restrict__ w_ff2, const float* __restrict__ w_act,
    _Float16* __restrict__ P) {
  int i = blockIdx.x * 256 + threadIdx.x;
  if (i >= PACK_TOTAL) return;
  float v;
  if (i < OFF_QKV) {                       // w_go [96k][96n] -> [n][k]
    int o = i, n = o / 96, k = o % 96;
    v = w_go[k * 96 + n];
  } else if (i < OFF_PROJ) {               // wq/wk/wv -> [l][c=288][d=96]
    int o = i - OFF_QKV;
    int l = o / 27648, r = o % 27648, c = r / 96, d = r % 96;
    int which = c / 96;
    int hc = c % 96, h = hc >> 4, j = hc & 15;
    const float* s = (which == 0) ? wq : (which == 1 ? wk : wv);
    v = s[((l * NH_ + h) * 96 + d) * 16 + j];
    if (which == 0) v *= QSCALE;
  } else if (i < OFF_FF1) {                // w_proj [l][96k][96n] -> [l][n][k]
    int o = i - OFF_PROJ;
    int l = o / 9216, r = o % 9216, n = r / 96, k = r % 96;
    v = w_proj[l * 9216 + k * 96 + n];
  } else if (i < OFF_FF2) {                // w_ff1 [l][96k][384n] -> [l][n][k]
    int o = i - OFF_FF1;
    int l = o / 36864, r = o % 36864, n = r / 96, k = r % 96;
    v = w_ff1[l * 36864 + k * 384 + n];
  } else if (i < OFF_ACT) {                // w_ff2 [l][384k][96n] -> [l][n][k]
    int o = i - OFF_FF2;
    int l = o / 36864, r = o % 36864, n = r / 384, k = r % 384;
    v = w_ff2[l * 36864 + k * 96 + n];
  } else {                                 // w_act [96k][16n] -> [n][k]
    int o = i - OFF_ACT;
    int n = o / 96, k = o % 96;
    v = w_act[k * 16 + n];
  }
  P[i] = (_Float16)v;
}

// ---------- fused stage kernel, 3 waves cooperate on 16 tokens ----------
// wave w owns col-frags {2w, 2w+1} of D=96; ff1 hidden frags 8w..8w+7;
// tail frags 6w..6w+5 (w0=Q, w1=K, w2=V). LDS exchanges between phases.
template <bool EMBED, bool HEAD>
__global__ __launch_bounds__(192, 3) void stage_kernel(
    const float* __restrict__ goals, const float* __restrict__ obss,
    const float* __restrict__ pos, const float* __restrict__ b_go,
    const _Float16* __restrict__ obh, const _Float16* __restrict__ Wp,
    const float* __restrict__ bp, float* __restrict__ x,
    const _Float16* __restrict__ W1, const float* __restrict__ b1,
    const _Float16* __restrict__ W2, const float* __restrict__ b2,
    const float* __restrict__ ln2g, const float* __restrict__ ln2b,
    const float* __restrict__ lntg, const float* __restrict__ lntb,
    const _Float16* __restrict__ Wtail, const float* __restrict__ btail,
    _Float16* __restrict__ qh, _Float16* __restrict__ kh,
    _Float16* __restrict__ vt, float* __restrict__ out) {
  __shared__ _Float16 xsh[6 * 16 * 16];        // xn exchange (h4 frags)
  __shared__ float ysh[3 * 6 * 16 * 20];       // ff2 partials, stride 20 pad
  __shared__ float lnsh[2][3][16][2];          // LN partial (s, sq)
  int tid = threadIdx.x;
  int wave = tid / 64, lane = tid & 63;
  int lr = lane & 15, lg = lane >> 4;
  int row0 = blockIdx.x * 16;
  int token = row0 + lr;
  int bidx = token >> 10, t = token & 1023;
  int c0 = wave * 2;
  const f4 zero4 = {0.f, 0.f, 0.f, 0.f};

  f4 xc[2];  // own 2 col-frag chunks of the residual value
  if constexpr (EMBED) {
    h4 ef[6];
#pragma unroll
    for (int st = 0; st < 6; ++st) {
      int k0 = st * 16 + lg * 4;
      f4 s4;
      if (st < 2) s4 = *(const f4*)(goals + bidx * 32 + k0);
      else        s4 = *(const f4*)(obss + (size_t)(bidx * 1024 + t) * 64 + (k0 - 32));
      ef[st] = (h4){(_Float16)s4[0], (_Float16)s4[1], (_Float16)s4[2], (_Float16)s4[3]};
    }
#pragma unroll
    for (int i = 0; i < 2; ++i) {
      int cf = c0 + i;
      f4 a = zero4;
      const _Float16* wrow = Wp + (size_t)(cf * 16 + lr) * 96 + lg * 4;
#pragma unroll
      for (int st = 0; st < 6; ++st) {
        h4 wf = *(const h4*)(wrow + st * 16);
        a = __builtin_amdgcn_mfma_f32_16x16x16f16(wf, ef[st], a, 0, 0, 0);
      }
      f4 bb = *(const f4*)(b_go + cf * 16 + lg * 4);
      f4 pp = *(const f4*)(pos + (size_t)t * 96 + cf * 16 + lg * 4);
#pragma unroll
      for (int j = 0; j < 4; ++j) xc[i][j] = a[j] + bb[j] + pp[j];
      *(f4*)(x + (size_t)token * 96 + cf * 16 + lg * 4) = xc[i];
    }
  } else {
    // ---- proj + resid (own 2 col-frags, full K) ----
    h4 obf[6];
    const _Float16* orow = obh + (size_t)token * 96 + lg * 4;
#pragma unroll
    for (int st = 0; st < 6; ++st) obf[st] = *(const h4*)(orow + st * 16);
    f4 x1[2];
#pragma unroll
    for (int i = 0; i < 2; ++i) {
      int cf = c0 + i;
      f4 a = zero4;
      const _Float16* wrow = Wp + (size_t)(cf * 16 + lr) * 96 + lg * 4;
#pragma unroll
      for (int st = 0; st < 6; ++st) {
        h4 wf = *(const h4*)(wrow + st * 16);
        a = __builtin_amdgcn_mfma_f32_16x16x16f16(wf, obf[st], a, 0, 0, 0);
      }
      f4 bb = *(const f4*)(bp + cf * 16 + lg * 4);
      f4 xr4 = *(const f4*)(x + (size_t)token * 96 + cf * 16 + lg * 4);
#pragma unroll
      for (int j = 0; j < 4; ++j) x1[i][j] = a[j] + bb[j] + xr4[j];
    }
    // ---- LN2: cross-wave stats via LDS ----
    {
      float s = 0.f, sq = 0.f;
#pragma unroll
      for (int i = 0; i < 2; ++i)
#pragma unroll
        for (int j = 0; j < 4; ++j) { s += x1[i][j]; sq += x1[i][j] * x1[i][j]; }
      s += __shfl_xor(s, 16); sq += __shfl_xor(sq, 16);
      s += __shfl_xor(s, 32); sq += __shfl_xor(sq, 32);
      if (lane < 16) { lnsh[0][wave][lr][0] = s; lnsh[0][wave][lr][1] = sq; }
    }
    __syncthreads();
    {
      float s = lnsh[0][0][lr][0] + lnsh[0][1][lr][0] + lnsh[0][2][lr][0];
      float sq = lnsh[0][0][lr][1] + lnsh[0][1][lr][1] + lnsh[0][2][lr][1];
      float mean = s * (1.f / 96.f);
      float rs = rsqrtf(sq * (1.f / 96.f) - mean * mean + 1e-5f);
#pragma unroll
      for (int i = 0; i < 2; ++i) {
        int cf = c0 + i;
        f4 g4 = *(const f4*)(ln2g + cf * 16 + lg * 4);
        f4 b4 = *(const f4*)(ln2b + cf * 16 + lg * 4);
        h4 xn;
#pragma unroll
        for (int j = 0; j < 4; ++j)
          xn[j] = (_Float16)((x1[i][j] - mean) * rs * g4[j] + b4[j]);
        *(h4*)&xsh[(cf * 16 + lr) * 16 + lg * 4] = xn;
      }
    }
    __syncthreads();
    h4 xnf[6];
#pragma unroll
    for (int cf = 0; cf < 6; ++cf)
      xnf[cf] = *(const h4*)&xsh[(cf * 16 + lr) * 16 + lg * 4];

    // ---- ff1 + relu (own 8 hidden frags) ----
    int nf0 = wave * 8;
    h4 hf[8];
#pragma unroll
    for (int f = 0; f < 8; ++f) {
      f4 h = zero4;
      const _Float16* wrow = W1 + (size_t)((nf0 + f) * 16 + lr) * 96 + lg * 4;
#pragma unroll
      for (int st = 0; st < 6; ++st) {
        h4 wf = *(const h4*)(wrow + st * 16);
        h = __builtin_amdgcn_mfma_f32_16x16x16f16(wf, xnf[st], h, 0, 0, 0);
      }
      f4 bb = *(const f4*)(b1 + (nf0 + f) * 16 + lg * 4);
#pragma unroll
      for (int j = 0; j < 4; ++j)
        hf[f][j] = (_Float16)fmaxf(h[j] + bb[j], 0.f);
    }

    // ---- ff2: K-split partials, LDS reduce ----
    f4 yown[2];
#pragma unroll
    for (int mf = 0; mf < 6; ++mf) {
      f4 y = zero4;
      const _Float16* wrow = W2 + (size_t)(mf * 16 + lr) * 384 + nf0 * 16 + lg * 4;
#pragma unroll
      for (int f = 0; f < 8; ++f) {
        h4 wf = *(const h4*)(wrow + f * 16);
        y = __builtin_amdgcn_mfma_f32_16x16x16f16(wf, hf[f], y, 0, 0, 0);
      }
      if ((mf >> 1) == wave) yown[mf & 1] = y;
      else *(f4*)&ysh[((wave * 6 + mf) * 16 + lr) * 20 + lg * 4] = y;
    }
    __syncthreads();
#pragma unroll
    for (int i = 0; i < 2; ++i) {
      int mf = c0 + i;
      f4 tot = yown[i];
#pragma unroll
      for (int ow = 0; ow < 3; ++ow)
        if (ow != wave)
          tot += *(const f4*)&ysh[((ow * 6 + mf) * 16 + lr) * 20 + lg * 4];
      f4 bb = *(const f4*)(b2 + mf * 16 + lg * 4);
#pragma unroll
      for (int j = 0; j < 4; ++j) xc[i][j] = x1[i][j] + tot[j] + bb[j];
      if constexpr (!HEAD)
        *(f4*)(x + (size_t)token * 96 + mf * 16 + lg * 4) = xc[i];
    }
  }

  // ---- tail LN on xc ----
  constexpr int ph = EMBED ? 0 : 1;
  {
    float s = 0.f, sq = 0.f;
#pragma unroll
    for (int i = 0; i < 2; ++i)
#pragma unroll
      for (int j = 0; j < 4; ++j) { s += xc[i][j]; sq += xc[i][j] * xc[i][j]; }
    s += __shfl_xor(s, 16); sq += __shfl_xor(sq, 16);
    s += __shfl_xor(s, 32); sq += __shfl_xor(sq, 32);
    if (lane < 16) { lnsh[ph][wave][lr][0] = s; lnsh[ph][wave][lr][1] = sq; }
  }
  __syncthreads();
  {
    float s = lnsh[ph][0][lr][0] + lnsh[ph][1][lr][0] + lnsh[ph][2][lr][0];
    float sq = lnsh[ph][0][lr][1] + lnsh[ph][1][lr][1] + lnsh[ph][2][lr][1];
    float mean = s * (1.f / 96.f);
    float rs = rsqrtf(sq * (1.f / 96.f) - mean * mean + 1e-5f);
#pragma unroll
    for (int i = 0; i < 2; ++i) {
      int cf = c0 + i;
      f4 g4 = *(const f4*)(lntg + cf * 16 + lg * 4);
      f4 b4 = *(const f4*)(lntb + cf * 16 + lg * 4);
      h4 xn;
#pragma unroll
      for (int j = 0; j < 4; ++j)
        xn[j] = (_Float16)((xc[i][j] - mean) * rs * g4[j] + b4[j]);
      *(h4*)&xsh[(cf * 16 + lr) * 16 + lg * 4] = xn;
    }
  }
  __syncthreads();
  h4 xf[6];
#pragma unroll
  for (int cf = 0; cf < 6; ++cf)
    xf[cf] = *(const h4*)&xsh[(cf * 16 + lr) * 16 + lg * 4];

  if constexpr (HEAD) {
    if (wave == 0) {
      f4 a = zero4;
      const _Float16* wrow = Wtail + (size_t)lr * 96 + lg * 4;
#pragma unroll
      for (int st = 0; st < 6; ++st) {
        h4 wf = *(const h4*)(wrow + st * 16);
        a = __builtin_amdgcn_mfma_f32_16x16x16f16(wf, xf[st], a, 0, 0, 0);
      }
      f4 bb = *(const f4*)(btail + lg * 4);
      f4 o;
#pragma unroll
      for (int j = 0; j < 4; ++j) o[j] = a[j] + bb[j];
      *(f4*)(out + (size_t)token * 16 + lg * 4) = o;
    }
  } else {
    // qkv: wave0 -> Q frags 0..5, wave1 -> K, wave2 -> V
#pragma unroll
    for (int f = 0; f < 6; ++f) {
      int nf = wave * 6 + f;
      f4 a = zero4;
      const _Float16* wrow = Wtail + (size_t)(nf * 16 + lr) * 96 + lg * 4;
#pragma unroll
      for (int st = 0; st < 6; ++st) {
        h4 wf = *(const h4*)(wrow + st * 16);
        a = __builtin_amdgcn_mfma_f32_16x16x16f16(wf, xf[st], a, 0, 0, 0);
      }
      if (wave < 2) {  // Q or K: [bh][t][16]
        _Float16* dst = (wave == 0 ? qh : kh) +
                        (size_t)(bidx * NH_ + f) * 16384 + (size_t)t * 16 + lg * 4;
        h4 hv = {(_Float16)a[0], (_Float16)a[1], (_Float16)a[2], (_Float16)a[3]};
        *(h4*)dst = hv;
      } else {         // V: [bh][d][1024]
        _Float16* dst = vt + (size_t)(bidx * NH_ + f) * 16384 + (size_t)(lg * 4) * 1024 + t;
#pragma unroll
        for (int r = 0; r < 4; ++r) dst[(size_t)r * 1024] = (_Float16)a[r];
      }
    }
  }
}

// ---------- MFMA f16 flash attention, fixed-max softmax, 16-row waves ------
__global__ __launch_bounds__(256, 6) void attn_mfma_kernel(
    const _Float16* __restrict__ Qh, const _Float16* __restrict__ Kh,
    const _Float16* __restrict__ Vt, _Float16* __restrict__ obh) {
  int bh = blockIdx.x;
  int wave = threadIdx.x >> 6;
  int lane = threadIdx.x & 63;
  int qt = wave * 16 + blockIdx.y;   // 0..63
  int q0 = qt * 16;
  int lr = lane & 15;
  int lg = lane >> 4;

  const _Float16* qb = Qh + (size_t)bh * 16384;
  const _Float16* kb = Kh + (size_t)bh * 16384;
  const _Float16* vb = Vt + (size_t)bh * 16384;

  h4 qf = *(const h4*)(qb + (size_t)(q0 + lr) * 16 + lg * 4);
  f4 O0 = {0.f, 0.f, 0.f, 0.f}, O1 = {0.f, 0.f, 0.f, 0.f};
  float lsum = 0.f;
  const f4 zero4 = {0.f, 0.f, 0.f, 0.f};

  int ntiles = qt / 2 + 1;
  h4 kc0, kc1, vc0, vc1, kn0, kn1, vn0, vn1;
  kc0 = *(const h4*)(kb + (size_t)lr * 16 + lg * 4);
  kc1 = *(const h4*)(kb + (size_t)(16 + lr) * 16 + lg * 4);
  vc0 = *(const h4*)(vb + (size_t)lr * 1024 + lg * 4);
  vc1 = *(const h4*)(vb + (size_t)lr * 1024 + 16 + lg * 4);

  for (int tt = 0; tt < ntiles; ++tt) {
    int s0 = tt * 32;
    bool last = (tt == ntiles - 1);
    if (!last) {
      int s1 = s0 + 32;
      kn0 = *(const h4*)(kb + (size_t)(s1 + lr) * 16 + lg * 4);
      kn1 = *(const h4*)(kb + (size_t)(s1 + 16 + lr) * 16 + lg * 4);
      vn0 = *(const h4*)(vb + (size_t)lr * 1024 + s1 + lg * 4);
      vn1 = *(const h4*)(vb + (size_t)lr * 1024 + s1 + 16 + lg * 4);
    }
    bool act1 = (s0 + 16 <= q0 + 15);
    f4 st0 = __builtin_amdgcn_mfma_f32_16x16x16f16(kc0, qf, zero4, 0, 0, 0);
    if (last) {
      int qi = q0 + lr;
#pragma unroll
      for (int r = 0; r < 4; ++r)
        if (s0 + lg * 4 + r > qi) st0[r] = -1e30f;
    }
    float p0[4];
#pragma unroll
    for (int r = 0; r < 4; ++r) {
      p0[r] = __builtin_amdgcn_exp2f(st0[r]);
      lsum += p0[r];
    }
    h4 pf0 = {(_Float16)p0[0], (_Float16)p0[1], (_Float16)p0[2], (_Float16)p0[3]};
    O0 = __builtin_amdgcn_mfma_f32_16x16x16f16(pf0, vc0, O0, 0, 0, 0);
    if (act1) {
      f4 st1 = __builtin_amdgcn_mfma_f32_16x16x16f16(kc1, qf, zero4, 0, 0, 0);
      if (last) {
        int qi = q0 + lr;
#pragma unroll
        for (int r = 0; r < 4; ++r)
          if (s0 + 16 + lg * 4 + r > qi) st1[r] = -1e30f;
      }
      float p1[4];
#pragma unroll
      for (int r = 0; r < 4; ++r) {
        p1[r] = __builtin_amdgcn_exp2f(st1[r]);
        lsum += p1[r];
      }
      h4 pf1 = {(_Float16)p1[0], (_Float16)p1[1], (_Float16)p1[2], (_Float16)p1[3]};
      O1 = __builtin_amdgcn_mfma_f32_16x16x16f16(pf1, vc1, O1, 0, 0, 0);
    }
    if (!last) { kc0 = kn0; kc1 = kn1; vc0 = vn0; vc1 = vn1; }
  }
  lsum += __shfl_xor(lsum, 16);
  lsum += __shfl_xor(lsum, 32);
  float linv = 1.f / lsum;
  int b = bh / NH_, h = bh % NH_;
#pragma unroll
  for (int r = 0; r < 4; ++r) {
    float li = __shfl(linv, lg * 4 + r);
    int q = q0 + lg * 4 + r;
    obh[(size_t)(b * 1024 + q) * 96 + h * 16 + lr] =
        (_Float16)((O0[r] + O1[r]) * li);
  }
}

extern "C" void kernel_launch(void* const* d_in, const int* in_sizes, int n_in,
                              void* d_out, int out_size, void* d_ws, size_t ws_size,
                              hipStream_t stream) {
  const float* goals   = (const float*)d_in[0];
  const float* obss    = (const float*)d_in[1];
  const float* w_go    = (const float*)d_in[2];
  const float* b_go    = (const float*)d_in[3];
  const float* pos_emb = (const float*)d_in[4];
  const float* wq      = (const float*)d_in[5];
  const float* wk      = (const float*)d_in[6];
  const float* wv      = (const float*)d_in[7];
  const float* w_proj  = (const float*)d_in[8];
  const float* b_proj  = (const float*)d_in[9];
  const float* ln1_g   = (const float*)d_in[10];
  const float* ln1_b   = (const float*)d_in[11];
  const float* ln2_g   = (const float*)d_in[12];
  const float* ln2_b   = (const float*)d_in[13];
  const float* w_ff1   = (const float*)d_in[14];
  const float* b_ff1   = (const float*)d_in[15];
  const float* w_ff2   = (const float*)d_in[16];
  const float* b_ff2   = (const float*)d_in[17];
  const float* lnf_g   = (const float*)d_in[18];
  const float* lnf_b   = (const float*)d_in[19];
  const float* w_act   = (const float*)d_in[20];
  const float* b_act   = (const float*)d_in[21];
  float* out = (float*)d_out;

  const int M = B_ * T_;  // 16384
  float* ws = (float*)d_ws;
  size_t off = 0;
  _Float16* P = (_Float16*)(ws + off); off += PACK_TOTAL / 2 + 64;
  float* x = ws + off; off += (size_t)M * 96;
  _Float16* obh = (_Float16*)(ws + off); off += (size_t)M * 48;
  _Float16* Qh = (_Float16*)(ws + off); off += (size_t)M * 48;
  _Float16* Kh = (_Float16*)(ws + off); off += (size_t)M * 48;
  _Float16* Vt = (_Float16*)(ws + off); off += (size_t)M * 48;

  pack_all_kernel<<<(PACK_TOTAL + 255) / 256, 256, 0, stream>>>(
      w_go, wq, wk, wv, w_proj, w_ff1, w_ff2, w_act, P);

  // embed + qkv(layer 0)
  stage_kernel<true, false><<<M / 16, 192, 0, stream>>>(
      goals, obss, pos_emb, b_go, nullptr, P + OFF_GO, nullptr, x,
      nullptr, nullptr, nullptr, nullptr, nullptr, nullptr,
      ln1_g, ln1_b, P + OFF_QKV, nullptr, Qh, Kh, Vt, nullptr);

  for (int l = 0; l < L_; ++l) {
    attn_mfma_kernel<<<dim3(B_ * NH_, 16), 256, 0, stream>>>(Qh, Kh, Vt, obh);
    if (l < L_ - 1) {
      stage_kernel<false, false><<<M / 16, 192, 0, stream>>>(
          nullptr, nullptr, nullptr, nullptr, obh,
          P + OFF_PROJ + (size_t)l * 9216, b_proj + l * 96, x,
          P + OFF_FF1 + (size_t)l * 36864, b_ff1 + l * 384,
          P + OFF_FF2 + (size_t)l * 36864, b_ff2 + l * 96,
          ln2_g + l * 96, ln2_b + l * 96,
          ln1_g + (l + 1) * 96, ln1_b + (l + 1) * 96,
          P + OFF_QKV + (size_t)(l + 1) * 27648, nullptr, Qh, Kh, Vt, nullptr);
    } else {
      stage_kernel<false, true><<<M / 16, 192, 0, stream>>>(
          nullptr, nullptr, nullptr, nullptr, obh,
          P + OFF_PROJ + (size_t)l * 9216, b_proj + l * 96, x,
          P + OFF_FF1 + (size_t)l * 36864, b_ff1 + l * 384,
          P + OFF_FF2 + (size_t)l * 36864, b_ff2 + l * 96,
          ln2_g + l * 96, ln2_b + l * 96,
          lnf_g, lnf_b, P + OFF_ACT, b_act, nullptr, nullptr, nullptr, out);
    }
  }
}